// Round 3
// baseline (10772.559 us; speedup 1.0000x reference)
//
#include <hip/hip_runtime.h>
#include <hip/hip_bf16.h>
#include <math.h>

constexpr int kT = 64, kB = 256, kS = 1024, kA = 32, kH = 2048;
constexpr int kH3 = 3 * kH;   // 6144
constexpr int kS2 = 2 * kS;   // 2048

typedef __hip_bfloat16 bf16;
typedef __bf16 bf16x8 __attribute__((ext_vector_type(8)));
typedef float f32x4 __attribute__((ext_vector_type(4)));

__device__ inline f32x4 mfma16(bf16x8 a, bf16x8 b, f32x4 c) {
  return __builtin_amdgcn_mfma_f32_16x16x32_bf16(a, b, c, 0, 0, 0);
}

__device__ inline void gload16(const void* g, void* l) {
  __builtin_amdgcn_global_load_lds(
      (const __attribute__((address_space(1))) void*)g,
      (__attribute__((address_space(3))) void*)l, 16, 0, 0);
}

// Device-scope grid barrier (sense/generation). All blocks must be resident:
// grid=128, LDS<=64KB, __launch_bounds__(256,2) => capacity >= 512 blocks.
__device__ __forceinline__ void grid_barrier(unsigned* cnt, unsigned* gen, unsigned nblk) {
  __syncthreads();
  if (threadIdx.x == 0) {
    __threadfence();  // release: make this block's stores visible device-wide
    unsigned g = __hip_atomic_load(gen, __ATOMIC_RELAXED, __HIP_MEMORY_SCOPE_AGENT);
    unsigned t = __hip_atomic_fetch_add(cnt, 1u, __ATOMIC_ACQ_REL, __HIP_MEMORY_SCOPE_AGENT);
    if (t == nblk - 1u) {
      __hip_atomic_store(cnt, 0u, __ATOMIC_RELAXED, __HIP_MEMORY_SCOPE_AGENT);
      __hip_atomic_fetch_add(gen, 1u, __ATOMIC_RELEASE, __HIP_MEMORY_SCOPE_AGENT);
    } else {
      while (__hip_atomic_load(gen, __ATOMIC_ACQUIRE, __HIP_MEMORY_SCOPE_AGENT) == g)
        __builtin_amdgcn_s_sleep(2);
    }
    __threadfence();  // acquire: invalidate caches before reading others' data
  }
  __syncthreads();
}

__global__ void k_zero(unsigned* p, int n) {
  int i = blockIdx.x * 64 + threadIdx.x;
  if (i < n) p[i] = 0u;
}

// Stage a [ROWS][64] bf16 tile into LDS with XOR-swizzle (T2/m173 pattern):
// LDS dest linear (global_load_lds requirement); global SOURCE chunk within
// each row pre-permuted by (row&7) so the swizzled ds_read is conflict-free.
template<int ROWS>
__device__ inline void stage_tile_sw(const bf16* __restrict__ g, int ldK, bf16* lds) {
  const int tid = threadIdx.x;
  const int wv = tid >> 6;
#pragma unroll
  for (int i = 0; i < ROWS / 32; ++i) {
    const int idx = i * 256 + tid;            // 16B-chunk id
    const int r = idx >> 3;
    const int cc = (idx & 7) ^ (r & 7);       // pre-swizzled source chunk
    gload16(g + (size_t)r * ldK + cc * 8, lds + (size_t)(i * 4 + wv) * 512);
  }
}

// Swizzled fragment read: lane l -> row row0+(l&15), k = ks*32 + (l>>4)*8.
__device__ inline bf16x8 ldfrag_sw(const bf16* lds, int row0, int ks) {
  const int lane = threadIdx.x & 63;
  const int row = row0 + (lane & 15);
  const int chunk = (ks * 4 + (lane >> 4)) ^ (row & 7);
  return *reinterpret_cast<const bf16x8*>(lds + row * 64 + chunk * 8);
}

// ---------- prep kernels ----------

__global__ void k_cvt(const float* __restrict__ src, bf16* __restrict__ dst, int n) {
  int i = (blockIdx.x * 256 + threadIdx.x) * 4;
  if (i >= n) return;
  float4 v = *reinterpret_cast<const float4*>(src + i);
  dst[i + 0] = __float2bfloat16(v.x);
  dst[i + 1] = __float2bfloat16(v.y);
  dst[i + 2] = __float2bfloat16(v.z);
  dst[i + 3] = __float2bfloat16(v.w);
}

__global__ void k_cvt_belief(const float* __restrict__ src, bf16* __restrict__ dstb,
                             float* __restrict__ dstf, int n) {
  int i = (blockIdx.x * 256 + threadIdx.x) * 4;
  if (i >= n) return;
  float4 v = *reinterpret_cast<const float4*>(src + i);
  dstb[i + 0] = __float2bfloat16(v.x);
  dstb[i + 1] = __float2bfloat16(v.y);
  dstb[i + 2] = __float2bfloat16(v.z);
  dstb[i + 3] = __float2bfloat16(v.w);
  *reinterpret_cast<float4*>(dstf + i) = v;
}

// src [R][C] f32 -> dst [C][R] bf16
__global__ __launch_bounds__(256) void k_transpose(const float* __restrict__ src,
                                                   bf16* __restrict__ dst, int R, int C) {
  __shared__ float tile[32][33];
  const int c0 = blockIdx.x * 32, r0 = blockIdx.y * 32;
  const int tx = threadIdx.x & 31, ty = threadIdx.x >> 5;
#pragma unroll
  for (int i = 0; i < 32; i += 8)
    tile[ty + i][tx] = src[(size_t)(r0 + ty + i) * C + c0 + tx];
  __syncthreads();
#pragma unroll
  for (int i = 0; i < 32; i += 8)
    dst[(size_t)(c0 + ty + i) * R + r0 + tx] = __float2bfloat16(tile[tx][ty + i]);
}

// actb[tb][h] = b_tp[h] + sum_a actions[tb][a] * Wtpa[a][h]   (K=32)
__global__ __launch_bounds__(256) void k_actb(const float* __restrict__ actions,
                                              const float* __restrict__ Wtpa,
                                              const float* __restrict__ b_tp,
                                              bf16* __restrict__ actb) {
  __shared__ float a_s[32];
  const int tb = blockIdx.x;
  const int tid = threadIdx.x;
  if (tid < 32) a_s[tid] = actions[(size_t)tb * 32 + tid];
  __syncthreads();
#pragma unroll
  for (int j = 0; j < 8; ++j) {
    int h = j * 256 + tid;
    float acc = b_tp[h];
#pragma unroll
    for (int a = 0; a < 32; ++a) acc += a_s[a] * Wtpa[a * kH + h];
    actb[(size_t)tb * kH + h] = __float2bfloat16(acc);
  }
}

// ---------- phase A: persistent state/hidden chain (software grid barrier) ----------
// 128 wgs: rb(4 row-blocks of 64) x cb(32 col-blocks), XCD-affine cb mapping.

__global__ __launch_bounds__(256, 2) void k_stateP(
    bf16* __restrict__ stateb, const bf16* __restrict__ WtpT,
    const bf16* __restrict__ actb, bf16* __restrict__ hidden,
    const bf16* __restrict__ WpostT, const float* __restrict__ b_post,
    const float* __restrict__ eps, float* __restrict__ out_means,
    float* __restrict__ out_stds, float* __restrict__ out_states,
    unsigned* __restrict__ bar) {
  __shared__ __align__(16) bf16 As[2][64 * 64];
  __shared__ __align__(16) bf16 Bs[2][64 * 64];
  const int bx = blockIdx.x;
  const int xcd = bx & 7, idx = bx >> 3;
  const int rb = idx >> 2;              // 0..3
  const int cb = xcd * 4 + (idx & 3);   // 0..31 (XCD-affine)
  const int m0 = rb * 64;
  const int tid = threadIdx.x, wv = tid >> 6, lane = tid & 63;
  const int l16 = lane & 15, k8 = lane >> 4;
  const int wr = (wv >> 1) * 32;

  for (int t = 0; t < kT; ++t) {
    // ---- hidden = relu(state @ WtpT^T + actb_t), cols [cb*64, +64)
    {
      const int n0 = cb * 64, wc = (wv & 1) * 32;
      f32x4 acc[2][2] = {};
      stage_tile_sw<64>(stateb + (size_t)m0 * kS, kS, As[0]);
      stage_tile_sw<64>(WtpT + (size_t)n0 * kS, kS, Bs[0]);
      __syncthreads();
      for (int kt = 0; kt < kS / 64; ++kt) {
        const int cur = kt & 1;
        if (kt + 1 < kS / 64) {
          stage_tile_sw<64>(stateb + (size_t)m0 * kS + (kt + 1) * 64, kS, As[cur ^ 1]);
          stage_tile_sw<64>(WtpT + (size_t)n0 * kS + (kt + 1) * 64, kS, Bs[cur ^ 1]);
        }
#pragma unroll
        for (int ks = 0; ks < 2; ++ks) {
          bf16x8 a0 = ldfrag_sw(As[cur], wr, ks), a1 = ldfrag_sw(As[cur], wr + 16, ks);
          bf16x8 b0 = ldfrag_sw(Bs[cur], wc, ks), b1 = ldfrag_sw(Bs[cur], wc + 16, ks);
          acc[0][0] = mfma16(a0, b0, acc[0][0]);
          acc[0][1] = mfma16(a0, b1, acc[0][1]);
          acc[1][0] = mfma16(a1, b0, acc[1][0]);
          acc[1][1] = mfma16(a1, b1, acc[1][1]);
        }
        __syncthreads();
      }
      const bf16* at = actb + (size_t)t * kB * kH;
      bf16* ht = hidden + (size_t)t * kB * kH;
#pragma unroll
      for (int mi = 0; mi < 2; ++mi)
#pragma unroll
        for (int ni = 0; ni < 2; ++ni)
#pragma unroll
          for (int ii = 0; ii < 4; ++ii) {
            int row = m0 + wr + mi * 16 + k8 * 4 + ii;
            int col = n0 + wc + ni * 16 + l16;
            float h = acc[mi][ni][ii] + __bfloat162float(at[(size_t)row * kH + col]);
            ht[(size_t)row * kH + col] = __float2bfloat16(fmaxf(h, 0.f));
          }
    }
    grid_barrier(bar + 0, bar + 1, gridDim.x);
    // ---- post: pair-block [cb*32, +32) of (mean j, std 1024+j)
    {
      const int p0 = cb * 32, wpc = (wv & 1) * 16;
      const bf16* ht = hidden + (size_t)t * kB * kH;
      f32x4 accM[2] = {}, accS[2] = {};
      stage_tile_sw<64>(ht + (size_t)m0 * kH, kH, As[0]);
      stage_tile_sw<32>(WpostT + (size_t)p0 * kH, kH, Bs[0]);
      stage_tile_sw<32>(WpostT + (size_t)(kS + p0) * kH, kH, Bs[0] + 32 * 64);
      __syncthreads();
      for (int kt = 0; kt < kH / 64; ++kt) {
        const int cur = kt & 1;
        if (kt + 1 < kH / 64) {
          stage_tile_sw<64>(ht + (size_t)m0 * kH + (kt + 1) * 64, kH, As[cur ^ 1]);
          stage_tile_sw<32>(WpostT + (size_t)p0 * kH + (kt + 1) * 64, kH, Bs[cur ^ 1]);
          stage_tile_sw<32>(WpostT + (size_t)(kS + p0) * kH + (kt + 1) * 64, kH,
                            Bs[cur ^ 1] + 32 * 64);
        }
#pragma unroll
        for (int ks = 0; ks < 2; ++ks) {
          bf16x8 a0 = ldfrag_sw(As[cur], wr, ks), a1 = ldfrag_sw(As[cur], wr + 16, ks);
          bf16x8 bm = ldfrag_sw(Bs[cur], wpc, ks);
          bf16x8 bsv = ldfrag_sw(Bs[cur] + 32 * 64, wpc, ks);
          accM[0] = mfma16(a0, bm, accM[0]);
          accM[1] = mfma16(a1, bm, accM[1]);
          accS[0] = mfma16(a0, bsv, accS[0]);
          accS[1] = mfma16(a1, bsv, accS[1]);
        }
        __syncthreads();
      }
      const float* et = eps + (size_t)t * kB * kS;
      float* mt = out_means + (size_t)t * kB * kS;
      float* sdt = out_stds + (size_t)t * kB * kS;
      float* xt = out_states + (size_t)t * kB * kS;
#pragma unroll
      for (int mi = 0; mi < 2; ++mi)
#pragma unroll
        for (int ii = 0; ii < 4; ++ii) {
          int row = m0 + wr + mi * 16 + k8 * 4 + ii;
          int p = p0 + wpc + l16;
          float mean = accM[mi][ii] + b_post[p];
          float sraw = accS[mi][ii] + b_post[kS + p];
          float sp = (sraw > 20.f) ? sraw : log1pf(expf(sraw));
          float sv = mean + sp * et[(size_t)row * kS + p];
          mt[(size_t)row * kS + p] = mean;
          sdt[(size_t)row * kS + p] = sp;
          xt[(size_t)row * kS + p] = sv;
          stateb[(size_t)row * kS + p] = __float2bfloat16(sv);
        }
    }
    grid_barrier(bar + 0, bar + 1, gridDim.x);
  }
}

// ---------- phase B: GI = hidden_chunk @ W_ih^T + b_ih (bf16 out) ----------

__global__ __launch_bounds__(256) void k_gi(const bf16* __restrict__ hidden_c,
                                            const bf16* __restrict__ Wih,
                                            const float* __restrict__ b_ih,
                                            bf16* __restrict__ GI) {
  __shared__ __align__(16) bf16 As[128 * 64];
  __shared__ __align__(16) bf16 Bs[128 * 64];
  const int m0 = blockIdx.y * 128, n0 = blockIdx.x * 128;
  const int tid = threadIdx.x, wv = tid >> 6, lane = tid & 63;
  const int l16 = lane & 15, k8 = lane >> 4;
  const int wr = (wv >> 1) * 64, wc = (wv & 1) * 64;
  f32x4 acc[4][4] = {};
  for (int kt = 0; kt < kH; kt += 64) {
    stage_tile_sw<128>(hidden_c + (size_t)m0 * kH + kt, kH, As);
    stage_tile_sw<128>(Wih + (size_t)n0 * kH + kt, kH, Bs);
    __syncthreads();
#pragma unroll
    for (int ks = 0; ks < 2; ++ks) {
      bf16x8 a[4], b[4];
#pragma unroll
      for (int i = 0; i < 4; ++i) a[i] = ldfrag_sw(As, wr + i * 16, ks);
#pragma unroll
      for (int i = 0; i < 4; ++i) b[i] = ldfrag_sw(Bs, wc + i * 16, ks);
#pragma unroll
      for (int mi = 0; mi < 4; ++mi)
#pragma unroll
        for (int ni = 0; ni < 4; ++ni)
          acc[mi][ni] = mfma16(a[mi], b[ni], acc[mi][ni]);
    }
    __syncthreads();
  }
#pragma unroll
  for (int mi = 0; mi < 4; ++mi)
#pragma unroll
    for (int ni = 0; ni < 4; ++ni)
#pragma unroll
      for (int ii = 0; ii < 4; ++ii) {
        int row = m0 + wr + mi * 16 + k8 * 4 + ii;
        int col = n0 + wc + ni * 16 + l16;
        GI[(size_t)row * kH3 + col] = __float2bfloat16(acc[mi][ni][ii] + b_ih[col]);
      }
}

// ---------- phase C: persistent GRU belief chain (software grid barrier) ----------

__global__ __launch_bounds__(256, 2) void k_gruP(
    const bf16* __restrict__ Whh, const float* __restrict__ b_hh,
    const bf16* __restrict__ GIb,          // [nsteps][B][3H] bf16
    float* __restrict__ belief_f32,
    float* __restrict__ out_beliefs_c,     // [nsteps][B][H]
    bf16* __restrict__ bb0, bf16* __restrict__ bb1,
    int s0, int nsteps, unsigned* __restrict__ bar) {
  __shared__ __align__(16) bf16 As[2][64 * 64];
  __shared__ __align__(16) bf16 Bs[2][3][64 * 64];
  const int bx = blockIdx.x;
  const int xcd = bx & 7, idx = bx >> 3;
  const int rb = idx >> 2;              // 0..3
  const int cb = xcd * 4 + (idx & 3);   // 0..31 (XCD-affine h-col blocks)
  const int m0 = rb * 64, n0 = cb * 64;
  const int tid = threadIdx.x, wv = tid >> 6, lane = tid & 63;
  const int l16 = lane & 15, k8 = lane >> 4;
  const int wr = (wv >> 1) * 32, wc = (wv & 1) * 32;

  for (int s = 0; s < nsteps; ++s) {
    const bf16* Ab = ((s0 + s) & 1) ? bb1 : bb0;
    bf16* Bn = ((s0 + s) & 1) ? bb0 : bb1;
    f32x4 acc[3][2][2] = {};
    stage_tile_sw<64>(Ab + (size_t)m0 * kH, kH, As[0]);
#pragma unroll
    for (int g = 0; g < 3; ++g)
      stage_tile_sw<64>(Whh + (size_t)(g * kH + n0) * kH, kH, Bs[0][g]);
    __syncthreads();
    for (int kt = 0; kt < kH / 64; ++kt) {
      const int cur = kt & 1;
      if (kt + 1 < kH / 64) {
        stage_tile_sw<64>(Ab + (size_t)m0 * kH + (kt + 1) * 64, kH, As[cur ^ 1]);
#pragma unroll
        for (int g = 0; g < 3; ++g)
          stage_tile_sw<64>(Whh + (size_t)(g * kH + n0) * kH + (kt + 1) * 64, kH,
                            Bs[cur ^ 1][g]);
      }
#pragma unroll
      for (int ks = 0; ks < 2; ++ks) {
        bf16x8 a0 = ldfrag_sw(As[cur], wr, ks), a1 = ldfrag_sw(As[cur], wr + 16, ks);
#pragma unroll
        for (int g = 0; g < 3; ++g) {
          bf16x8 b0 = ldfrag_sw(Bs[cur][g], wc, ks), b1 = ldfrag_sw(Bs[cur][g], wc + 16, ks);
          acc[g][0][0] = mfma16(a0, b0, acc[g][0][0]);
          acc[g][0][1] = mfma16(a0, b1, acc[g][0][1]);
          acc[g][1][0] = mfma16(a1, b0, acc[g][1][0]);
          acc[g][1][1] = mfma16(a1, b1, acc[g][1][1]);
        }
      }
      __syncthreads();
    }
    const bf16* GIt = GIb + (size_t)s * kB * kH3;
    float* outB = out_beliefs_c + (size_t)s * kB * kH;
#pragma unroll
    for (int mi = 0; mi < 2; ++mi)
#pragma unroll
      for (int ni = 0; ni < 2; ++ni)
#pragma unroll
        for (int ii = 0; ii < 4; ++ii) {
          int row = m0 + wr + mi * 16 + k8 * 4 + ii;
          int col = n0 + wc + ni * 16 + l16;
          const bf16* gi = GIt + (size_t)row * kH3;
          float hr = acc[0][mi][ni][ii] + b_hh[col];
          float hz = acc[1][mi][ni][ii] + b_hh[kH + col];
          float hn = acc[2][mi][ni][ii] + b_hh[2 * kH + col];
          float r = 1.f / (1.f + expf(-(__bfloat162float(gi[col]) + hr)));
          float z = 1.f / (1.f + expf(-(__bfloat162float(gi[kH + col]) + hz)));
          float n = tanhf(__bfloat162float(gi[2 * kH + col]) + r * hn);
          float bel = belief_f32[(size_t)row * kH + col];
          float nb = (1.f - z) * n + z * bel;
          outB[(size_t)row * kH + col] = nb;
          belief_f32[(size_t)row * kH + col] = nb;
          Bn[(size_t)row * kH + col] = __float2bfloat16(nb);
        }
    grid_barrier(bar + 0, bar + 1, gridDim.x);
  }
}

// ---------- host ----------

extern "C" void kernel_launch(void* const* d_in, const int* in_sizes, int n_in,
                              void* d_out, int out_size, void* d_ws, size_t ws_size,
                              hipStream_t stream) {
  const float* prev_state  = (const float*)d_in[0];
  const float* actions     = (const float*)d_in[1];
  const float* prev_belief = (const float*)d_in[2];
  const float* eps         = (const float*)d_in[3];
  const float* W_ih        = (const float*)d_in[4];
  const float* W_hh        = (const float*)d_in[5];
  const float* b_ih        = (const float*)d_in[6];
  const float* b_hh        = (const float*)d_in[7];
  const float* W_tp        = (const float*)d_in[8];
  const float* b_tp        = (const float*)d_in[9];
  const float* W_post      = (const float*)d_in[10];
  const float* b_post      = (const float*)d_in[11];

  float* out_beliefs = (float*)d_out;                          // [T,B,H]
  float* out_states  = out_beliefs + (size_t)kT * kB * kH;     // [T,B,S]
  float* out_means   = out_states + (size_t)kT * kB * kS;
  float* out_stds    = out_means + (size_t)kT * kB * kS;

  size_t off = 0;
  auto alloc = [&](size_t bytes) {
    void* r = (char*)d_ws + off;
    off += (bytes + 255) & ~(size_t)255;
    return r;
  };
  unsigned* bar = (unsigned*)alloc(256);   // [cntA, genA, cntC, genC]
  bf16* Wih_b  = (bf16*)alloc((size_t)kH3 * kH * 2);
  bf16* Whh_b  = (bf16*)alloc((size_t)kH3 * kH * 2);
  bf16* WtpT   = (bf16*)alloc((size_t)kH * kS * 2);   // [H][S]
  bf16* WpostT = (bf16*)alloc((size_t)kS2 * kH * 2);  // [2S][H]
  bf16* actb   = (bf16*)alloc((size_t)kT * kB * kH * 2);
  bf16* hidden = (bf16*)alloc((size_t)kT * kB * kH * 2);
  bf16* stateb = (bf16*)alloc((size_t)kB * kS * 2);
  bf16* bb0    = (bf16*)alloc((size_t)kB * kH * 2);
  bf16* bb1    = (bf16*)alloc((size_t)kB * kH * 2);
  float* belief_f32 = (float*)alloc((size_t)kB * kH * 4);
  size_t base = off;
  int CH = 64;
  while (CH > 1 && base + (size_t)CH * kB * kH3 * 2 > ws_size) CH >>= 1;
  bf16* GI = (bf16*)alloc((size_t)CH * kB * kH3 * 2);

  // zero barrier state (ws is poisoned 0xAA once; gen-based barrier self-cleans after)
  k_zero<<<dim3(1), dim3(64), 0, stream>>>(bar, 4);

  // prep
  k_cvt<<<dim3(kH3 * kH / 1024), 256, 0, stream>>>(W_ih, Wih_b, kH3 * kH);
  k_cvt<<<dim3(kH3 * kH / 1024), 256, 0, stream>>>(W_hh, Whh_b, kH3 * kH);
  k_cvt<<<dim3(kB * kS / 1024), 256, 0, stream>>>(prev_state, stateb, kB * kS);
  k_cvt_belief<<<dim3(kB * kH / 1024), 256, 0, stream>>>(prev_belief, bb0, belief_f32, kB * kH);
  k_transpose<<<dim3(kH / 32, kS / 32), 256, 0, stream>>>(W_tp, WtpT, kS, kH);
  k_transpose<<<dim3(kS2 / 32, kH / 32), 256, 0, stream>>>(W_post, WpostT, kH, kS2);
  k_actb<<<dim3(kT * kB), 256, 0, stream>>>(actions, W_tp + (size_t)kS * kH, b_tp, actb);

  // phase A: persistent state/hidden chain (one launch, 64 steps, software barrier)
  k_stateP<<<dim3(128), dim3(256), 0, stream>>>(
      stateb, WtpT, actb, hidden, WpostT, b_post, eps,
      out_means, out_stds, out_states, bar);

  // phase B (big batched gi GEMM, chunked by ws) + phase C (persistent belief chain)
  for (int c0 = 0; c0 < kT; c0 += CH) {
    k_gi<<<dim3(kH3 / 128, CH * kB / 128), 256, 0, stream>>>(
        hidden + (size_t)c0 * kB * kH, Wih_b, b_ih, GI);
    k_gruP<<<dim3(128), dim3(256), 0, stream>>>(
        Whh_b, b_hh, GI, belief_f32, out_beliefs + (size_t)c0 * kB * kH,
        bb0, bb1, c0, CH, bar + 2);
  }
}

// Round 4
// 9247.015 us; speedup vs baseline: 1.1650x; 1.1650x over previous
//
#include <hip/hip_runtime.h>
#include <hip/hip_bf16.h>
#include <math.h>

constexpr int kT = 64, kB = 256, kS = 1024, kA = 32, kH = 2048;
constexpr int kH3 = 3 * kH;   // 6144
constexpr int kS2 = 2 * kS;   // 2048

typedef __hip_bfloat16 bf16;
typedef __bf16 bf16x8 __attribute__((ext_vector_type(8)));
typedef float f32x4 __attribute__((ext_vector_type(4)));

__device__ inline f32x4 mfma16(bf16x8 a, bf16x8 b, f32x4 c) {
  return __builtin_amdgcn_mfma_f32_16x16x32_bf16(a, b, c, 0, 0, 0);
}

__device__ inline void gload16(const void* g, void* l) {
  __builtin_amdgcn_global_load_lds(
      (const __attribute__((address_space(1))) void*)g,
      (__attribute__((address_space(3))) void*)l, 16, 0, 0);
}

// Stage a [ROWS][64] bf16 tile into LDS with XOR-swizzle (T2/m173 pattern):
// LDS dest linear (global_load_lds requirement); global SOURCE chunk within
// each row pre-permuted by (row&7) so the swizzled ds_read is conflict-free.
template<int ROWS>
__device__ inline void stage_tile_sw(const bf16* __restrict__ g, int ldK, bf16* lds) {
  const int tid = threadIdx.x;
  const int wv = tid >> 6;
#pragma unroll
  for (int i = 0; i < ROWS / 32; ++i) {
    const int idx = i * 256 + tid;            // 16B-chunk id
    const int r = idx >> 3;
    const int cc = (idx & 7) ^ (r & 7);       // pre-swizzled source chunk
    gload16(g + (size_t)r * ldK + cc * 8, lds + (size_t)(i * 4 + wv) * 512);
  }
}

// Swizzled fragment read: lane l -> row row0+(l&15), k = ks*32 + (l>>4)*8.
__device__ inline bf16x8 ldfrag_sw(const bf16* lds, int row0, int ks) {
  const int lane = threadIdx.x & 63;
  const int row = row0 + (lane & 15);
  const int chunk = (ks * 4 + (lane >> 4)) ^ (row & 7);
  return *reinterpret_cast<const bf16x8*>(lds + row * 64 + chunk * 8);
}

// ---------- prep kernels ----------

__global__ void k_cvt(const float* __restrict__ src, bf16* __restrict__ dst, int n) {
  int i = (blockIdx.x * 256 + threadIdx.x) * 4;
  if (i >= n) return;
  float4 v = *reinterpret_cast<const float4*>(src + i);
  dst[i + 0] = __float2bfloat16(v.x);
  dst[i + 1] = __float2bfloat16(v.y);
  dst[i + 2] = __float2bfloat16(v.z);
  dst[i + 3] = __float2bfloat16(v.w);
}

__global__ void k_cvt_belief(const float* __restrict__ src, bf16* __restrict__ dstb,
                             float* __restrict__ dstf, int n) {
  int i = (blockIdx.x * 256 + threadIdx.x) * 4;
  if (i >= n) return;
  float4 v = *reinterpret_cast<const float4*>(src + i);
  dstb[i + 0] = __float2bfloat16(v.x);
  dstb[i + 1] = __float2bfloat16(v.y);
  dstb[i + 2] = __float2bfloat16(v.z);
  dstb[i + 3] = __float2bfloat16(v.w);
  *reinterpret_cast<float4*>(dstf + i) = v;
}

// src [R][C] f32 -> dst [C][R] bf16
__global__ __launch_bounds__(256) void k_transpose(const float* __restrict__ src,
                                                   bf16* __restrict__ dst, int R, int C) {
  __shared__ float tile[32][33];
  const int c0 = blockIdx.x * 32, r0 = blockIdx.y * 32;
  const int tx = threadIdx.x & 31, ty = threadIdx.x >> 5;
#pragma unroll
  for (int i = 0; i < 32; i += 8)
    tile[ty + i][tx] = src[(size_t)(r0 + ty + i) * C + c0 + tx];
  __syncthreads();
#pragma unroll
  for (int i = 0; i < 32; i += 8)
    dst[(size_t)(c0 + ty + i) * R + r0 + tx] = __float2bfloat16(tile[tx][ty + i]);
}

// actb[tb][h] = b_tp[h] + sum_a actions[tb][a] * Wtpa[a][h]   (K=32)
__global__ __launch_bounds__(256) void k_actb(const float* __restrict__ actions,
                                              const float* __restrict__ Wtpa,
                                              const float* __restrict__ b_tp,
                                              bf16* __restrict__ actb) {
  __shared__ float a_s[32];
  const int tb = blockIdx.x;
  const int tid = threadIdx.x;
  if (tid < 32) a_s[tid] = actions[(size_t)tb * 32 + tid];
  __syncthreads();
#pragma unroll
  for (int j = 0; j < 8; ++j) {
    int h = j * 256 + tid;
    float acc = b_tp[h];
#pragma unroll
    for (int a = 0; a < 32; ++a) acc += a_s[a] * Wtpa[a * kH + h];
    actb[(size_t)tb * kH + h] = __float2bfloat16(acc);
  }
}

// ---------- phase A, step kernel 1: hidden = relu(state @ WtpT^T + actb_t) ----------
// M=256,N=2048,K=1024; 128x128 tiles, grid (16, 2), double-buffered.

__global__ __launch_bounds__(256) void k_hidden(const bf16* __restrict__ stateb,
                                                const bf16* __restrict__ WtpT,
                                                const bf16* __restrict__ actb_t,
                                                bf16* __restrict__ hidden_t) {
  __shared__ __align__(16) bf16 As[2][128 * 64];
  __shared__ __align__(16) bf16 Bs[2][128 * 64];
  const int m0 = blockIdx.y * 128, n0 = blockIdx.x * 128;
  const int tid = threadIdx.x, wv = tid >> 6, lane = tid & 63;
  const int l16 = lane & 15, k8 = lane >> 4;
  const int wr = (wv >> 1) * 64, wc = (wv & 1) * 64;
  f32x4 acc[4][4] = {};
  stage_tile_sw<128>(stateb + (size_t)m0 * kS, kS, As[0]);
  stage_tile_sw<128>(WtpT + (size_t)n0 * kS, kS, Bs[0]);
  __syncthreads();
  for (int kt = 0; kt < kS / 64; ++kt) {
    const int cur = kt & 1;
    if (kt + 1 < kS / 64) {
      stage_tile_sw<128>(stateb + (size_t)m0 * kS + (kt + 1) * 64, kS, As[cur ^ 1]);
      stage_tile_sw<128>(WtpT + (size_t)n0 * kS + (kt + 1) * 64, kS, Bs[cur ^ 1]);
    }
#pragma unroll
    for (int ks = 0; ks < 2; ++ks) {
      bf16x8 a[4], b[4];
#pragma unroll
      for (int i = 0; i < 4; ++i) a[i] = ldfrag_sw(As[cur], wr + i * 16, ks);
#pragma unroll
      for (int i = 0; i < 4; ++i) b[i] = ldfrag_sw(Bs[cur], wc + i * 16, ks);
#pragma unroll
      for (int mi = 0; mi < 4; ++mi)
#pragma unroll
        for (int ni = 0; ni < 4; ++ni)
          acc[mi][ni] = mfma16(a[mi], b[ni], acc[mi][ni]);
    }
    __syncthreads();
  }
#pragma unroll
  for (int mi = 0; mi < 4; ++mi)
#pragma unroll
    for (int ni = 0; ni < 4; ++ni)
#pragma unroll
      for (int ii = 0; ii < 4; ++ii) {
        int row = m0 + wr + mi * 16 + k8 * 4 + ii;
        int col = n0 + wc + ni * 16 + l16;
        float h = acc[mi][ni][ii] + __bfloat162float(actb_t[(size_t)row * kH + col]);
        hidden_t[(size_t)row * kH + col] = __float2bfloat16(fmaxf(h, 0.f));
      }
}

// ---------- phase A, step kernel 2: post (mean/std/state) ----------
// 64 rows x 64 pairs, grid (16, 4), double-buffered, two B tiles (mean, std).

__global__ __launch_bounds__(256) void k_post(const bf16* __restrict__ hidden_t,
                                              const bf16* __restrict__ WpostT,
                                              const float* __restrict__ b_post,
                                              const float* __restrict__ eps_t,
                                              float* __restrict__ means_t,
                                              float* __restrict__ stds_t,
                                              float* __restrict__ states_t,
                                              bf16* __restrict__ stateb) {
  __shared__ __align__(16) bf16 As[2][64 * 64];
  __shared__ __align__(16) bf16 BsM[2][64 * 64];
  __shared__ __align__(16) bf16 BsS[2][64 * 64];
  const int m0 = blockIdx.y * 64, p0 = blockIdx.x * 64;
  const int tid = threadIdx.x, wv = tid >> 6, lane = tid & 63;
  const int l16 = lane & 15, k8 = lane >> 4;
  const int wr = (wv >> 1) * 32, wc = (wv & 1) * 32;
  f32x4 accM[2][2] = {}, accS[2][2] = {};
  stage_tile_sw<64>(hidden_t + (size_t)m0 * kH, kH, As[0]);
  stage_tile_sw<64>(WpostT + (size_t)p0 * kH, kH, BsM[0]);
  stage_tile_sw<64>(WpostT + (size_t)(kS + p0) * kH, kH, BsS[0]);
  __syncthreads();
  for (int kt = 0; kt < kH / 64; ++kt) {
    const int cur = kt & 1;
    if (kt + 1 < kH / 64) {
      stage_tile_sw<64>(hidden_t + (size_t)m0 * kH + (kt + 1) * 64, kH, As[cur ^ 1]);
      stage_tile_sw<64>(WpostT + (size_t)p0 * kH + (kt + 1) * 64, kH, BsM[cur ^ 1]);
      stage_tile_sw<64>(WpostT + (size_t)(kS + p0) * kH + (kt + 1) * 64, kH, BsS[cur ^ 1]);
    }
#pragma unroll
    for (int ks = 0; ks < 2; ++ks) {
      bf16x8 a0 = ldfrag_sw(As[cur], wr, ks), a1 = ldfrag_sw(As[cur], wr + 16, ks);
#pragma unroll
      for (int ni = 0; ni < 2; ++ni) {
        bf16x8 bm = ldfrag_sw(BsM[cur], wc + ni * 16, ks);
        bf16x8 bs = ldfrag_sw(BsS[cur], wc + ni * 16, ks);
        accM[0][ni] = mfma16(a0, bm, accM[0][ni]);
        accM[1][ni] = mfma16(a1, bm, accM[1][ni]);
        accS[0][ni] = mfma16(a0, bs, accS[0][ni]);
        accS[1][ni] = mfma16(a1, bs, accS[1][ni]);
      }
    }
    __syncthreads();
  }
#pragma unroll
  for (int mi = 0; mi < 2; ++mi)
#pragma unroll
    for (int ni = 0; ni < 2; ++ni)
#pragma unroll
      for (int ii = 0; ii < 4; ++ii) {
        int row = m0 + wr + mi * 16 + k8 * 4 + ii;
        int p = p0 + wc + ni * 16 + l16;
        float mean = accM[mi][ni][ii] + b_post[p];
        float sraw = accS[mi][ni][ii] + b_post[kS + p];
        float sp = (sraw > 20.f) ? sraw : log1pf(expf(sraw));
        float sv = mean + sp * eps_t[(size_t)row * kS + p];
        means_t[(size_t)row * kS + p] = mean;
        stds_t[(size_t)row * kS + p] = sp;
        states_t[(size_t)row * kS + p] = sv;
        stateb[(size_t)row * kS + p] = __float2bfloat16(sv);
      }
}

// ---------- phase B: GI = hidden_chunk @ W_ih^T + b_ih (bf16 out) ----------

__global__ __launch_bounds__(256) void k_gi(const bf16* __restrict__ hidden_c,
                                            const bf16* __restrict__ Wih,
                                            const float* __restrict__ b_ih,
                                            bf16* __restrict__ GI) {
  __shared__ __align__(16) bf16 As[128 * 64];
  __shared__ __align__(16) bf16 Bs[128 * 64];
  const int m0 = blockIdx.y * 128, n0 = blockIdx.x * 128;
  const int tid = threadIdx.x, wv = tid >> 6, lane = tid & 63;
  const int l16 = lane & 15, k8 = lane >> 4;
  const int wr = (wv >> 1) * 64, wc = (wv & 1) * 64;
  f32x4 acc[4][4] = {};
  for (int kt = 0; kt < kH; kt += 64) {
    stage_tile_sw<128>(hidden_c + (size_t)m0 * kH + kt, kH, As);
    stage_tile_sw<128>(Wih + (size_t)n0 * kH + kt, kH, Bs);
    __syncthreads();
#pragma unroll
    for (int ks = 0; ks < 2; ++ks) {
      bf16x8 a[4], b[4];
#pragma unroll
      for (int i = 0; i < 4; ++i) a[i] = ldfrag_sw(As, wr + i * 16, ks);
#pragma unroll
      for (int i = 0; i < 4; ++i) b[i] = ldfrag_sw(Bs, wc + i * 16, ks);
#pragma unroll
      for (int mi = 0; mi < 4; ++mi)
#pragma unroll
        for (int ni = 0; ni < 4; ++ni)
          acc[mi][ni] = mfma16(a[mi], b[ni], acc[mi][ni]);
    }
    __syncthreads();
  }
#pragma unroll
  for (int mi = 0; mi < 4; ++mi)
#pragma unroll
    for (int ni = 0; ni < 4; ++ni)
#pragma unroll
      for (int ii = 0; ii < 4; ++ii) {
        int row = m0 + wr + mi * 16 + k8 * 4 + ii;
        int col = n0 + wc + ni * 16 + l16;
        GI[(size_t)row * kH3 + col] = __float2bfloat16(acc[mi][ni][ii] + b_ih[col]);
      }
}

// ---------- phase C: per-step GRU (gh GEMM + fused elementwise) ----------
// M=128 rows x (64 h-cols x 3 gates), grid (32, 2), double-buffered.
// bx%8 gives XCD-affine h-col slices so each XCD's W_hh slice stays L2-resident.

__global__ __launch_bounds__(256) void k_gru(const bf16* __restrict__ beliefb,
                                             const bf16* __restrict__ Whh,
                                             const float* __restrict__ b_hh,
                                             const bf16* __restrict__ GI_t,
                                             float* __restrict__ belief_f32,
                                             float* __restrict__ beliefs_out_t,
                                             bf16* __restrict__ beliefb_next) {
  __shared__ __align__(16) bf16 As[2][128 * 64];
  __shared__ __align__(16) bf16 Bs[2][3][64 * 64];
  const int m0 = blockIdx.y * 128, n0 = blockIdx.x * 64;
  const int tid = threadIdx.x, wv = tid >> 6, lane = tid & 63;
  const int l16 = lane & 15, k8 = lane >> 4;
  const int wr = (wv >> 1) * 64, wc = (wv & 1) * 32;
  f32x4 acc[3][4][2] = {};
  stage_tile_sw<128>(beliefb + (size_t)m0 * kH, kH, As[0]);
#pragma unroll
  for (int g = 0; g < 3; ++g)
    stage_tile_sw<64>(Whh + (size_t)(g * kH + n0) * kH, kH, Bs[0][g]);
  __syncthreads();
  for (int kt = 0; kt < kH / 64; ++kt) {
    const int cur = kt & 1;
    if (kt + 1 < kH / 64) {
      stage_tile_sw<128>(beliefb + (size_t)m0 * kH + (kt + 1) * 64, kH, As[cur ^ 1]);
#pragma unroll
      for (int g = 0; g < 3; ++g)
        stage_tile_sw<64>(Whh + (size_t)(g * kH + n0) * kH + (kt + 1) * 64, kH,
                          Bs[cur ^ 1][g]);
    }
#pragma unroll
    for (int ks = 0; ks < 2; ++ks) {
      bf16x8 a[4];
#pragma unroll
      for (int i = 0; i < 4; ++i) a[i] = ldfrag_sw(As[cur], wr + i * 16, ks);
#pragma unroll
      for (int g = 0; g < 3; ++g)
#pragma unroll
        for (int ni = 0; ni < 2; ++ni) {
          bf16x8 b = ldfrag_sw(Bs[cur][g], wc + ni * 16, ks);
#pragma unroll
          for (int mi = 0; mi < 4; ++mi)
            acc[g][mi][ni] = mfma16(a[mi], b, acc[g][mi][ni]);
        }
    }
    __syncthreads();
  }
#pragma unroll
  for (int mi = 0; mi < 4; ++mi)
#pragma unroll
    for (int ni = 0; ni < 2; ++ni)
#pragma unroll
      for (int ii = 0; ii < 4; ++ii) {
        int row = m0 + wr + mi * 16 + k8 * 4 + ii;
        int col = n0 + wc + ni * 16 + l16;
        const bf16* gi = GI_t + (size_t)row * kH3;
        float hr = acc[0][mi][ni][ii] + b_hh[col];
        float hz = acc[1][mi][ni][ii] + b_hh[kH + col];
        float hn = acc[2][mi][ni][ii] + b_hh[2 * kH + col];
        float r = 1.f / (1.f + expf(-(__bfloat162float(gi[col]) + hr)));
        float z = 1.f / (1.f + expf(-(__bfloat162float(gi[kH + col]) + hz)));
        float n = tanhf(__bfloat162float(gi[2 * kH + col]) + r * hn);
        float bel = belief_f32[(size_t)row * kH + col];
        float nb = (1.f - z) * n + z * bel;
        beliefs_out_t[(size_t)row * kH + col] = nb;
        belief_f32[(size_t)row * kH + col] = nb;
        beliefb_next[(size_t)row * kH + col] = __float2bfloat16(nb);
      }
}

// ---------- host ----------

extern "C" void kernel_launch(void* const* d_in, const int* in_sizes, int n_in,
                              void* d_out, int out_size, void* d_ws, size_t ws_size,
                              hipStream_t stream) {
  const float* prev_state  = (const float*)d_in[0];
  const float* actions     = (const float*)d_in[1];
  const float* prev_belief = (const float*)d_in[2];
  const float* eps         = (const float*)d_in[3];
  const float* W_ih        = (const float*)d_in[4];
  const float* W_hh        = (const float*)d_in[5];
  const float* b_ih        = (const float*)d_in[6];
  const float* b_hh        = (const float*)d_in[7];
  const float* W_tp        = (const float*)d_in[8];
  const float* b_tp        = (const float*)d_in[9];
  const float* W_post      = (const float*)d_in[10];
  const float* b_post      = (const float*)d_in[11];

  float* out_beliefs = (float*)d_out;                          // [T,B,H]
  float* out_states  = out_beliefs + (size_t)kT * kB * kH;     // [T,B,S]
  float* out_means   = out_states + (size_t)kT * kB * kS;
  float* out_stds    = out_means + (size_t)kT * kB * kS;

  size_t off = 0;
  auto alloc = [&](size_t bytes) {
    void* r = (char*)d_ws + off;
    off += (bytes + 255) & ~(size_t)255;
    return r;
  };
  bf16* Wih_b  = (bf16*)alloc((size_t)kH3 * kH * 2);
  bf16* Whh_b  = (bf16*)alloc((size_t)kH3 * kH * 2);
  bf16* WtpT   = (bf16*)alloc((size_t)kH * kS * 2);   // [H][S]
  bf16* WpostT = (bf16*)alloc((size_t)kS2 * kH * 2);  // [2S][H]
  bf16* actb   = (bf16*)alloc((size_t)kT * kB * kH * 2);
  bf16* hidden = (bf16*)alloc((size_t)kT * kB * kH * 2);
  bf16* stateb = (bf16*)alloc((size_t)kB * kS * 2);
  bf16* bb0    = (bf16*)alloc((size_t)kB * kH * 2);
  bf16* bb1    = (bf16*)alloc((size_t)kB * kH * 2);
  bf16* bb[2]  = {bb0, bb1};
  float* belief_f32 = (float*)alloc((size_t)kB * kH * 4);
  size_t base = off;
  int CH = 64;
  while (CH > 1 && base + (size_t)CH * kB * kH3 * 2 > ws_size) CH >>= 1;
  bf16* GI = (bf16*)alloc((size_t)CH * kB * kH3 * 2);

  // prep
  k_cvt<<<dim3(kH3 * kH / 1024), 256, 0, stream>>>(W_ih, Wih_b, kH3 * kH);
  k_cvt<<<dim3(kH3 * kH / 1024), 256, 0, stream>>>(W_hh, Whh_b, kH3 * kH);
  k_cvt<<<dim3(kB * kS / 1024), 256, 0, stream>>>(prev_state, stateb, kB * kS);
  k_cvt_belief<<<dim3(kB * kH / 1024), 256, 0, stream>>>(prev_belief, bb0, belief_f32, kB * kH);
  k_transpose<<<dim3(kH / 32, kS / 32), 256, 0, stream>>>(W_tp, WtpT, kS, kH);
  k_transpose<<<dim3(kS2 / 32, kH / 32), 256, 0, stream>>>(W_post, WpostT, kH, kS2);
  k_actb<<<dim3(kT * kB), 256, 0, stream>>>(actions, W_tp + (size_t)kS * kH, b_tp, actb);

  // phase A: state/hidden chain (serial, 2 launches per step)
  for (int t = 0; t < kT; ++t) {
    k_hidden<<<dim3(kH / 128, kB / 128), 256, 0, stream>>>(
        stateb, WtpT, actb + (size_t)t * kB * kH, hidden + (size_t)t * kB * kH);
    k_post<<<dim3(kS / 64, kB / 64), 256, 0, stream>>>(
        hidden + (size_t)t * kB * kH, WpostT, b_post, eps + (size_t)t * kB * kS,
        out_means + (size_t)t * kB * kS, out_stds + (size_t)t * kB * kS,
        out_states + (size_t)t * kB * kS, stateb);
  }

  // phase B (big batched gi GEMM, chunked by ws) + phase C (serial GRU)
  for (int c0 = 0; c0 < kT; c0 += CH) {
    k_gi<<<dim3(kH3 / 128, CH * kB / 128), 256, 0, stream>>>(
        hidden + (size_t)c0 * kB * kH, Wih_b, b_ih, GI);
    for (int t = c0; t < c0 + CH; ++t) {
      k_gru<<<dim3(kH / 64, kB / 128), 256, 0, stream>>>(
          bb[t & 1], Whh_b, b_hh, GI + (size_t)(t - c0) * kB * kH3, belief_f32,
          out_beliefs + (size_t)t * kB * kH, bb[(t + 1) & 1]);
    }
  }
}

// Round 5
// 6471.626 us; speedup vs baseline: 1.6646x; 1.4289x over previous
//
#include <hip/hip_runtime.h>
#include <hip/hip_bf16.h>
#include <math.h>

constexpr int kT = 64, kB = 256, kS = 1024, kA = 32, kH = 2048;
constexpr int kH3 = 3 * kH;   // 6144
constexpr int kS2 = 2 * kS;   // 2048

typedef __hip_bfloat16 bf16;
typedef __bf16 bf16x8 __attribute__((ext_vector_type(8)));
typedef float f32x4 __attribute__((ext_vector_type(4)));

__device__ inline f32x4 mfma16(bf16x8 a, bf16x8 b, f32x4 c) {
  return __builtin_amdgcn_mfma_f32_16x16x32_bf16(a, b, c, 0, 0, 0);
}

__device__ inline void gload16(const void* g, void* l) {
  __builtin_amdgcn_global_load_lds(
      (const __attribute__((address_space(1))) void*)g,
      (__attribute__((address_space(3))) void*)l, 16, 0, 0);
}

// Stage a [ROWS][64] bf16 tile into LDS with XOR-swizzle (T2/m173 pattern):
// LDS dest linear (global_load_lds requirement); global SOURCE chunk within
// each row pre-permuted by (row&7) so the swizzled ds_read is conflict-free.
template<int ROWS>
__device__ inline void stage_tile_sw(const bf16* __restrict__ g, int ldK, bf16* lds) {
  const int tid = threadIdx.x;
  const int wv = tid >> 6;
#pragma unroll
  for (int i = 0; i < ROWS / 32; ++i) {
    const int idx = i * 256 + tid;            // 16B-chunk id
    const int r = idx >> 3;
    const int cc = (idx & 7) ^ (r & 7);       // pre-swizzled source chunk
    gload16(g + (size_t)r * ldK + cc * 8, lds + (size_t)(i * 4 + wv) * 512);
  }
}

// Swizzled fragment read: lane l -> row row0+(l&15), k = ks*32 + (l>>4)*8.
__device__ inline bf16x8 ldfrag_sw(const bf16* lds, int row0, int ks) {
  const int lane = threadIdx.x & 63;
  const int row = row0 + (lane & 15);
  const int chunk = (ks * 4 + (lane >> 4)) ^ (row & 7);
  return *reinterpret_cast<const bf16x8*>(lds + row * 64 + chunk * 8);
}

// ---------- prep kernels ----------

__global__ void k_cvt(const float* __restrict__ src, bf16* __restrict__ dst, int n) {
  int i = (blockIdx.x * 256 + threadIdx.x) * 4;
  if (i >= n) return;
  float4 v = *reinterpret_cast<const float4*>(src + i);
  dst[i + 0] = __float2bfloat16(v.x);
  dst[i + 1] = __float2bfloat16(v.y);
  dst[i + 2] = __float2bfloat16(v.z);
  dst[i + 3] = __float2bfloat16(v.w);
}

__global__ void k_cvt_belief(const float* __restrict__ src, bf16* __restrict__ dstb,
                             float* __restrict__ dstf, int n) {
  int i = (blockIdx.x * 256 + threadIdx.x) * 4;
  if (i >= n) return;
  float4 v = *reinterpret_cast<const float4*>(src + i);
  dstb[i + 0] = __float2bfloat16(v.x);
  dstb[i + 1] = __float2bfloat16(v.y);
  dstb[i + 2] = __float2bfloat16(v.z);
  dstb[i + 3] = __float2bfloat16(v.w);
  *reinterpret_cast<float4*>(dstf + i) = v;
}

// src [R][C] f32 -> dst [C][R] bf16
__global__ __launch_bounds__(256) void k_transpose(const float* __restrict__ src,
                                                   bf16* __restrict__ dst, int R, int C) {
  __shared__ float tile[32][33];
  const int c0 = blockIdx.x * 32, r0 = blockIdx.y * 32;
  const int tx = threadIdx.x & 31, ty = threadIdx.x >> 5;
#pragma unroll
  for (int i = 0; i < 32; i += 8)
    tile[ty + i][tx] = src[(size_t)(r0 + ty + i) * C + c0 + tx];
  __syncthreads();
#pragma unroll
  for (int i = 0; i < 32; i += 8)
    dst[(size_t)(c0 + ty + i) * R + r0 + tx] = __float2bfloat16(tile[tx][ty + i]);
}

// actb[tb][h] = b_tp[h] + sum_a actions[tb][a] * Wtpa[a][h]   (K=32)
// One block = 64 tb rows; actions cached in LDS; W row-slice in registers.
__global__ __launch_bounds__(256) void k_actb(const float* __restrict__ actions,
                                              const float* __restrict__ Wtpa,
                                              const float* __restrict__ b_tp,
                                              bf16* __restrict__ actb) {
  __shared__ float a_s[64][32];
  const int tb0 = blockIdx.x * 64;
  const int tid = threadIdx.x;
  for (int i = tid; i < 64 * 32 / 4; i += 256) {
    float4 v = *reinterpret_cast<const float4*>(actions + (size_t)tb0 * 32 + i * 4);
    reinterpret_cast<float4*>(&a_s[0][0])[i] = v;
  }
  __syncthreads();
#pragma unroll
  for (int j = 0; j < 8; ++j) {
    const int c = j * 256 + tid;
    float w[32];
#pragma unroll
    for (int a = 0; a < 32; ++a) w[a] = Wtpa[a * kH + c];
    const float bt = b_tp[c];
    for (int r = 0; r < 64; ++r) {
      float acc = bt;
#pragma unroll
      for (int a = 0; a < 32; ++a) acc += a_s[r][a] * w[a];
      actb[(size_t)(tb0 + r) * kH + c] = __float2bfloat16(acc);
    }
  }
}

// ---------- phase A, step kernel 1: hidden = relu(state @ WtpT^T + actb_t) ----------
// 64x64 tiles, grid (32,4) = 128 blocks; XCD-affine n0 so each XCD's 0.5 MB
// WtpT slice stays resident in its private L2 across all 64 steps.

__global__ __launch_bounds__(256) void k_hidden(const bf16* __restrict__ stateb,
                                                const bf16* __restrict__ WtpT,
                                                const bf16* __restrict__ actb_t,
                                                bf16* __restrict__ hidden_t) {
  __shared__ __align__(16) bf16 As[2][64 * 64];
  __shared__ __align__(16) bf16 Bs[2][64 * 64];
  const int bx = blockIdx.x;
  const int n0 = (bx & 7) * 256 + (bx >> 3) * 64;   // XCD-affine
  const int m0 = blockIdx.y * 64;
  const int tid = threadIdx.x, wv = tid >> 6, lane = tid & 63;
  const int l16 = lane & 15, k8 = lane >> 4;
  const int wr = (wv >> 1) * 32, wc = (wv & 1) * 32;
  f32x4 acc[2][2] = {};
  stage_tile_sw<64>(stateb + (size_t)m0 * kS, kS, As[0]);
  stage_tile_sw<64>(WtpT + (size_t)n0 * kS, kS, Bs[0]);
  __syncthreads();
  for (int kt = 0; kt < kS / 64; ++kt) {
    const int cur = kt & 1;
    if (kt + 1 < kS / 64) {
      stage_tile_sw<64>(stateb + (size_t)m0 * kS + (kt + 1) * 64, kS, As[cur ^ 1]);
      stage_tile_sw<64>(WtpT + (size_t)n0 * kS + (kt + 1) * 64, kS, Bs[cur ^ 1]);
    }
#pragma unroll
    for (int ks = 0; ks < 2; ++ks) {
      bf16x8 a0 = ldfrag_sw(As[cur], wr, ks), a1 = ldfrag_sw(As[cur], wr + 16, ks);
      bf16x8 b0 = ldfrag_sw(Bs[cur], wc, ks), b1 = ldfrag_sw(Bs[cur], wc + 16, ks);
      acc[0][0] = mfma16(a0, b0, acc[0][0]);
      acc[0][1] = mfma16(a0, b1, acc[0][1]);
      acc[1][0] = mfma16(a1, b0, acc[1][0]);
      acc[1][1] = mfma16(a1, b1, acc[1][1]);
    }
    __syncthreads();
  }
#pragma unroll
  for (int mi = 0; mi < 2; ++mi)
#pragma unroll
    for (int ni = 0; ni < 2; ++ni)
#pragma unroll
      for (int ii = 0; ii < 4; ++ii) {
        int row = m0 + wr + mi * 16 + k8 * 4 + ii;
        int col = n0 + wc + ni * 16 + l16;
        float h = acc[mi][ni][ii] + __bfloat162float(actb_t[(size_t)row * kH + col]);
        hidden_t[(size_t)row * kH + col] = __float2bfloat16(fmaxf(h, 0.f));
      }
}

// ---------- phase A, step kernel 2: post (mean/std/state) ----------
// 64 rows x 32 pairs, grid (32,4) = 128 blocks; XCD-affine p0 (1 MB/XCD slice).

__global__ __launch_bounds__(256) void k_post(const bf16* __restrict__ hidden_t,
                                              const bf16* __restrict__ WpostT,
                                              const float* __restrict__ b_post,
                                              const float* __restrict__ eps_t,
                                              float* __restrict__ means_t,
                                              float* __restrict__ stds_t,
                                              float* __restrict__ states_t,
                                              bf16* __restrict__ stateb) {
  __shared__ __align__(16) bf16 As[2][64 * 64];
  __shared__ __align__(16) bf16 BsM[2][32 * 64];
  __shared__ __align__(16) bf16 BsS[2][32 * 64];
  const int bx = blockIdx.x;
  const int p0 = (bx & 7) * 128 + (bx >> 3) * 32;   // XCD-affine pair block
  const int m0 = blockIdx.y * 64;
  const int tid = threadIdx.x, wv = tid >> 6, lane = tid & 63;
  const int l16 = lane & 15, k8 = lane >> 4;
  const int wr = (wv >> 1) * 32, wpc = (wv & 1) * 16;
  f32x4 accM[2] = {}, accS[2] = {};
  stage_tile_sw<64>(hidden_t + (size_t)m0 * kH, kH, As[0]);
  stage_tile_sw<32>(WpostT + (size_t)p0 * kH, kH, BsM[0]);
  stage_tile_sw<32>(WpostT + (size_t)(kS + p0) * kH, kH, BsS[0]);
  __syncthreads();
  for (int kt = 0; kt < kH / 64; ++kt) {
    const int cur = kt & 1;
    if (kt + 1 < kH / 64) {
      stage_tile_sw<64>(hidden_t + (size_t)m0 * kH + (kt + 1) * 64, kH, As[cur ^ 1]);
      stage_tile_sw<32>(WpostT + (size_t)p0 * kH + (kt + 1) * 64, kH, BsM[cur ^ 1]);
      stage_tile_sw<32>(WpostT + (size_t)(kS + p0) * kH + (kt + 1) * 64, kH, BsS[cur ^ 1]);
    }
#pragma unroll
    for (int ks = 0; ks < 2; ++ks) {
      bf16x8 a0 = ldfrag_sw(As[cur], wr, ks), a1 = ldfrag_sw(As[cur], wr + 16, ks);
      bf16x8 bm = ldfrag_sw(BsM[cur], wpc, ks);
      bf16x8 bs = ldfrag_sw(BsS[cur], wpc, ks);
      accM[0] = mfma16(a0, bm, accM[0]);
      accM[1] = mfma16(a1, bm, accM[1]);
      accS[0] = mfma16(a0, bs, accS[0]);
      accS[1] = mfma16(a1, bs, accS[1]);
    }
    __syncthreads();
  }
#pragma unroll
  for (int mi = 0; mi < 2; ++mi)
#pragma unroll
    for (int ii = 0; ii < 4; ++ii) {
      int row = m0 + wr + mi * 16 + k8 * 4 + ii;
      int p = p0 + wpc + l16;
      float mean = accM[mi][ii] + b_post[p];
      float sraw = accS[mi][ii] + b_post[kS + p];
      float sp = (sraw > 20.f) ? sraw : log1pf(expf(sraw));
      float sv = mean + sp * eps_t[(size_t)row * kS + p];
      means_t[(size_t)row * kS + p] = mean;
      stds_t[(size_t)row * kS + p] = sp;
      states_t[(size_t)row * kS + p] = sv;
      stateb[(size_t)row * kS + p] = __float2bfloat16(sv);
    }
}

// ---------- phase B: GI = hidden_chunk @ W_ih^T + b_ih (bf16 out) ----------
// XCD-affine n0: each XCD keeps its 3 MB Wih slice L2-resident across m-blocks.

__global__ __launch_bounds__(256) void k_gi(const bf16* __restrict__ hidden_c,
                                            const bf16* __restrict__ Wih,
                                            const float* __restrict__ b_ih,
                                            bf16* __restrict__ GI) {
  __shared__ __align__(16) bf16 As[128 * 64];
  __shared__ __align__(16) bf16 Bs[128 * 64];
  const int bx = blockIdx.x;
  const int n0 = (bx & 7) * 768 + (bx >> 3) * 128;  // XCD-affine (48 n-blocks)
  const int m0 = blockIdx.y * 128;
  const int tid = threadIdx.x, wv = tid >> 6, lane = tid & 63;
  const int l16 = lane & 15, k8 = lane >> 4;
  const int wr = (wv >> 1) * 64, wc = (wv & 1) * 64;
  f32x4 acc[4][4] = {};
  for (int kt = 0; kt < kH; kt += 64) {
    stage_tile_sw<128>(hidden_c + (size_t)m0 * kH + kt, kH, As);
    stage_tile_sw<128>(Wih + (size_t)n0 * kH + kt, kH, Bs);
    __syncthreads();
#pragma unroll
    for (int ks = 0; ks < 2; ++ks) {
      bf16x8 a[4], b[4];
#pragma unroll
      for (int i = 0; i < 4; ++i) a[i] = ldfrag_sw(As, wr + i * 16, ks);
#pragma unroll
      for (int i = 0; i < 4; ++i) b[i] = ldfrag_sw(Bs, wc + i * 16, ks);
#pragma unroll
      for (int mi = 0; mi < 4; ++mi)
#pragma unroll
        for (int ni = 0; ni < 4; ++ni)
          acc[mi][ni] = mfma16(a[mi], b[ni], acc[mi][ni]);
    }
    __syncthreads();
  }
#pragma unroll
  for (int mi = 0; mi < 4; ++mi)
#pragma unroll
    for (int ni = 0; ni < 4; ++ni)
#pragma unroll
      for (int ii = 0; ii < 4; ++ii) {
        int row = m0 + wr + mi * 16 + k8 * 4 + ii;
        int col = n0 + wc + ni * 16 + l16;
        GI[(size_t)row * kH3 + col] = __float2bfloat16(acc[mi][ni][ii] + b_ih[col]);
      }
}

// ---------- phase C: per-step GRU (gh GEMM + fused elementwise) ----------
// 64 rows x 64 h-cols x 3 gates, grid (32,4) = 128 blocks; XCD-affine n0 so
// each XCD's 3 MB W_hh slice stays in its private L2 across all 64 steps.

__global__ __launch_bounds__(256) void k_gru(const bf16* __restrict__ beliefb,
                                             const bf16* __restrict__ Whh,
                                             const float* __restrict__ b_hh,
                                             const bf16* __restrict__ GI_t,
                                             float* __restrict__ belief_f32,
                                             float* __restrict__ beliefs_out_t,
                                             bf16* __restrict__ beliefb_next) {
  __shared__ __align__(16) bf16 As[2][64 * 64];
  __shared__ __align__(16) bf16 Bs[2][3][64 * 64];
  const int bx = blockIdx.x;
  const int n0 = (bx & 7) * 256 + (bx >> 3) * 64;   // XCD-affine h-col block
  const int m0 = blockIdx.y * 64;
  const int tid = threadIdx.x, wv = tid >> 6, lane = tid & 63;
  const int l16 = lane & 15, k8 = lane >> 4;
  const int wr = (wv >> 1) * 32, wc = (wv & 1) * 32;
  f32x4 acc[3][2][2] = {};
  stage_tile_sw<64>(beliefb + (size_t)m0 * kH, kH, As[0]);
#pragma unroll
  for (int g = 0; g < 3; ++g)
    stage_tile_sw<64>(Whh + (size_t)(g * kH + n0) * kH, kH, Bs[0][g]);
  __syncthreads();
  for (int kt = 0; kt < kH / 64; ++kt) {
    const int cur = kt & 1;
    if (kt + 1 < kH / 64) {
      stage_tile_sw<64>(beliefb + (size_t)m0 * kH + (kt + 1) * 64, kH, As[cur ^ 1]);
#pragma unroll
      for (int g = 0; g < 3; ++g)
        stage_tile_sw<64>(Whh + (size_t)(g * kH + n0) * kH + (kt + 1) * 64, kH,
                          Bs[cur ^ 1][g]);
    }
#pragma unroll
    for (int ks = 0; ks < 2; ++ks) {
      bf16x8 a0 = ldfrag_sw(As[cur], wr, ks), a1 = ldfrag_sw(As[cur], wr + 16, ks);
#pragma unroll
      for (int g = 0; g < 3; ++g) {
        bf16x8 b0 = ldfrag_sw(Bs[cur][g], wc, ks), b1 = ldfrag_sw(Bs[cur][g], wc + 16, ks);
        acc[g][0][0] = mfma16(a0, b0, acc[g][0][0]);
        acc[g][0][1] = mfma16(a0, b1, acc[g][0][1]);
        acc[g][1][0] = mfma16(a1, b0, acc[g][1][0]);
        acc[g][1][1] = mfma16(a1, b1, acc[g][1][1]);
      }
    }
    __syncthreads();
  }
#pragma unroll
  for (int mi = 0; mi < 2; ++mi)
#pragma unroll
    for (int ni = 0; ni < 2; ++ni)
#pragma unroll
      for (int ii = 0; ii < 4; ++ii) {
        int row = m0 + wr + mi * 16 + k8 * 4 + ii;
        int col = n0 + wc + ni * 16 + l16;
        const bf16* gi = GI_t + (size_t)row * kH3;
        float hr = acc[0][mi][ni][ii] + b_hh[col];
        float hz = acc[1][mi][ni][ii] + b_hh[kH + col];
        float hn = acc[2][mi][ni][ii] + b_hh[2 * kH + col];
        float r = 1.f / (1.f + expf(-(__bfloat162float(gi[col]) + hr)));
        float z = 1.f / (1.f + expf(-(__bfloat162float(gi[kH + col]) + hz)));
        float n = tanhf(__bfloat162float(gi[2 * kH + col]) + r * hn);
        float bel = belief_f32[(size_t)row * kH + col];
        float nb = (1.f - z) * n + z * bel;
        beliefs_out_t[(size_t)row * kH + col] = nb;
        belief_f32[(size_t)row * kH + col] = nb;
        beliefb_next[(size_t)row * kH + col] = __float2bfloat16(nb);
      }
}

// ---------- host ----------

extern "C" void kernel_launch(void* const* d_in, const int* in_sizes, int n_in,
                              void* d_out, int out_size, void* d_ws, size_t ws_size,
                              hipStream_t stream) {
  const float* prev_state  = (const float*)d_in[0];
  const float* actions     = (const float*)d_in[1];
  const float* prev_belief = (const float*)d_in[2];
  const float* eps         = (const float*)d_in[3];
  const float* W_ih        = (const float*)d_in[4];
  const float* W_hh        = (const float*)d_in[5];
  const float* b_ih        = (const float*)d_in[6];
  const float* b_hh        = (const float*)d_in[7];
  const float* W_tp        = (const float*)d_in[8];
  const float* b_tp        = (const float*)d_in[9];
  const float* W_post      = (const float*)d_in[10];
  const float* b_post      = (const float*)d_in[11];

  float* out_beliefs = (float*)d_out;                          // [T,B,H]
  float* out_states  = out_beliefs + (size_t)kT * kB * kH;     // [T,B,S]
  float* out_means   = out_states + (size_t)kT * kB * kS;
  float* out_stds    = out_means + (size_t)kT * kB * kS;

  size_t off = 0;
  auto alloc = [&](size_t bytes) {
    void* r = (char*)d_ws + off;
    off += (bytes + 255) & ~(size_t)255;
    return r;
  };
  bf16* Wih_b  = (bf16*)alloc((size_t)kH3 * kH * 2);
  bf16* Whh_b  = (bf16*)alloc((size_t)kH3 * kH * 2);
  bf16* WtpT   = (bf16*)alloc((size_t)kH * kS * 2);   // [H][S]
  bf16* WpostT = (bf16*)alloc((size_t)kS2 * kH * 2);  // [2S][H]
  bf16* actb   = (bf16*)alloc((size_t)kT * kB * kH * 2);
  bf16* hidden = (bf16*)alloc((size_t)kT * kB * kH * 2);
  bf16* stateb = (bf16*)alloc((size_t)kB * kS * 2);
  bf16* bb0    = (bf16*)alloc((size_t)kB * kH * 2);
  bf16* bb1    = (bf16*)alloc((size_t)kB * kH * 2);
  bf16* bb[2]  = {bb0, bb1};
  float* belief_f32 = (float*)alloc((size_t)kB * kH * 4);
  size_t base = off;
  int CH = 64;
  while (CH > 1 && base + (size_t)CH * kB * kH3 * 2 > ws_size) CH >>= 1;
  bf16* GI = (bf16*)alloc((size_t)CH * kB * kH3 * 2);

  // prep
  k_cvt<<<dim3(kH3 * kH / 1024), 256, 0, stream>>>(W_ih, Wih_b, kH3 * kH);
  k_cvt<<<dim3(kH3 * kH / 1024), 256, 0, stream>>>(W_hh, Whh_b, kH3 * kH);
  k_cvt<<<dim3(kB * kS / 1024), 256, 0, stream>>>(prev_state, stateb, kB * kS);
  k_cvt_belief<<<dim3(kB * kH / 1024), 256, 0, stream>>>(prev_belief, bb0, belief_f32, kB * kH);
  k_transpose<<<dim3(kH / 32, kS / 32), 256, 0, stream>>>(W_tp, WtpT, kS, kH);
  k_transpose<<<dim3(kS2 / 32, kH / 32), 256, 0, stream>>>(W_post, WpostT, kH, kS2);
  k_actb<<<dim3(kT * kB / 64), 256, 0, stream>>>(actions, W_tp + (size_t)kS * kH, b_tp, actb);

  // phase A: state/hidden chain (serial, 2 launches per step)
  for (int t = 0; t < kT; ++t) {
    k_hidden<<<dim3(32, 4), 256, 0, stream>>>(
        stateb, WtpT, actb + (size_t)t * kB * kH, hidden + (size_t)t * kB * kH);
    k_post<<<dim3(32, 4), 256, 0, stream>>>(
        hidden + (size_t)t * kB * kH, WpostT, b_post, eps + (size_t)t * kB * kS,
        out_means + (size_t)t * kB * kS, out_stds + (size_t)t * kB * kS,
        out_states + (size_t)t * kB * kS, stateb);
  }

  // phase B (big batched gi GEMM, chunked by ws) + phase C (serial GRU)
  for (int c0 = 0; c0 < kT; c0 += CH) {
    k_gi<<<dim3(48, CH * kB / 128), 256, 0, stream>>>(
        hidden + (size_t)c0 * kB * kH, Wih_b, b_ih, GI);
    for (int t = c0; t < c0 + CH; ++t) {
      k_gru<<<dim3(32, 4), 256, 0, stream>>>(
          bb[t & 1], Whh_b, b_hh, GI + (size_t)(t - c0) * kB * kH3, belief_f32,
          out_beliefs + (size_t)t * kB * kH, bb[(t + 1) & 1]);
    }
  }
}

// Round 6
// 3658.846 us; speedup vs baseline: 2.9443x; 1.7688x over previous
//
#include <hip/hip_runtime.h>
#include <hip/hip_bf16.h>
#include <math.h>

constexpr int kT = 64, kB = 256, kS = 1024, kA = 32, kH = 2048;
constexpr int kH3 = 3 * kH;   // 6144
constexpr int kS2 = 2 * kS;   // 2048

typedef __hip_bfloat16 bf16;
typedef __bf16 bf16x8 __attribute__((ext_vector_type(8)));
typedef float f32x4 __attribute__((ext_vector_type(4)));

__device__ inline f32x4 mfma16(bf16x8 a, bf16x8 b, f32x4 c) {
  return __builtin_amdgcn_mfma_f32_16x16x32_bf16(a, b, c, 0, 0, 0);
}

__device__ inline void gload16(const void* g, void* l) {
  __builtin_amdgcn_global_load_lds(
      (const __attribute__((address_space(1))) void*)g,
      (__attribute__((address_space(3))) void*)l, 16, 0, 0);
}

// Stage a [ROWS][64] bf16 tile into LDS with XOR-swizzle (T2/m173 pattern):
// LDS dest linear (global_load_lds requirement); global SOURCE chunk within
// each row pre-permuted by (row&7) so the swizzled ds_read is conflict-free.
template<int ROWS>
__device__ inline void stage_tile_sw(const bf16* __restrict__ g, int ldK, bf16* lds) {
  const int tid = threadIdx.x;
  const int wv = tid >> 6;
#pragma unroll
  for (int i = 0; i < ROWS / 32; ++i) {
    const int idx = i * 256 + tid;            // 16B-chunk id
    const int r = idx >> 3;
    const int cc = (idx & 7) ^ (r & 7);       // pre-swizzled source chunk
    gload16(g + (size_t)r * ldK + cc * 8, lds + (size_t)(i * 4 + wv) * 512);
  }
}

// Swizzled fragment read: lane l -> row row0+(l&15), k = ks*32 + (l>>4)*8.
__device__ inline bf16x8 ldfrag_sw(const bf16* lds, int row0, int ks) {
  const int lane = threadIdx.x & 63;
  const int row = row0 + (lane & 15);
  const int chunk = (ks * 4 + (lane >> 4)) ^ (row & 7);
  return *reinterpret_cast<const bf16x8*>(lds + row * 64 + chunk * 8);
}

// ---------- prep kernels ----------

__global__ void k_cvt(const float* __restrict__ src, bf16* __restrict__ dst, int n) {
  int i = (blockIdx.x * 256 + threadIdx.x) * 4;
  if (i >= n) return;
  float4 v = *reinterpret_cast<const float4*>(src + i);
  dst[i + 0] = __float2bfloat16(v.x);
  dst[i + 1] = __float2bfloat16(v.y);
  dst[i + 2] = __float2bfloat16(v.z);
  dst[i + 3] = __float2bfloat16(v.w);
}

__global__ void k_cvt_belief(const float* __restrict__ src, bf16* __restrict__ dstb,
                             float* __restrict__ dstf, int n) {
  int i = (blockIdx.x * 256 + threadIdx.x) * 4;
  if (i >= n) return;
  float4 v = *reinterpret_cast<const float4*>(src + i);
  dstb[i + 0] = __float2bfloat16(v.x);
  dstb[i + 1] = __float2bfloat16(v.y);
  dstb[i + 2] = __float2bfloat16(v.z);
  dstb[i + 3] = __float2bfloat16(v.w);
  *reinterpret_cast<float4*>(dstf + i) = v;
}

// src [R][C] f32 -> dst [C][R] bf16
__global__ __launch_bounds__(256) void k_transpose(const float* __restrict__ src,
                                                   bf16* __restrict__ dst, int R, int C) {
  __shared__ float tile[32][33];
  const int c0 = blockIdx.x * 32, r0 = blockIdx.y * 32;
  const int tx = threadIdx.x & 31, ty = threadIdx.x >> 5;
#pragma unroll
  for (int i = 0; i < 32; i += 8)
    tile[ty + i][tx] = src[(size_t)(r0 + ty + i) * C + c0 + tx];
  __syncthreads();
#pragma unroll
  for (int i = 0; i < 32; i += 8)
    dst[(size_t)(c0 + ty + i) * R + r0 + tx] = __float2bfloat16(tile[tx][ty + i]);
}

// actb[tb][h] = b_tp[h] + sum_a actions[tb][a] * Wtpa[a][h]   (K=32)
__global__ __launch_bounds__(256) void k_actb(const float* __restrict__ actions,
                                              const float* __restrict__ Wtpa,
                                              const float* __restrict__ b_tp,
                                              bf16* __restrict__ actb) {
  __shared__ float a_s[64][32];
  const int tb0 = blockIdx.x * 64;
  const int tid = threadIdx.x;
  for (int i = tid; i < 64 * 32 / 4; i += 256) {
    float4 v = *reinterpret_cast<const float4*>(actions + (size_t)tb0 * 32 + i * 4);
    reinterpret_cast<float4*>(&a_s[0][0])[i] = v;
  }
  __syncthreads();
#pragma unroll
  for (int j = 0; j < 8; ++j) {
    const int c = j * 256 + tid;
    float w[32];
#pragma unroll
    for (int a = 0; a < 32; ++a) w[a] = Wtpa[a * kH + c];
    const float bt = b_tp[c];
    for (int r = 0; r < 64; ++r) {
      float acc = bt;
#pragma unroll
      for (int a = 0; a < 32; ++a) acc += a_s[r][a] * w[a];
      actb[(size_t)(tb0 + r) * kH + c] = __float2bfloat16(acc);
    }
  }
}

// ---------- fused step kernel 1: hidden(t) [blocks j<16] || gru(t-1) [j>=16] ----------
// 256 blocks. xcd = bx&7; j = bx>>3 in [0,32). XCD-affine column slices.

__global__ __launch_bounds__(256) void k_step1(
    const bf16* __restrict__ stateb, const bf16* __restrict__ WtpT,
    const bf16* __restrict__ actb_t, bf16* __restrict__ hidden_t, int doHidden,
    const bf16* __restrict__ Whh, const float* __restrict__ b_hh,
    const bf16* __restrict__ GIprev, float* __restrict__ belief_f32,
    float* __restrict__ outB_prev, const bf16* __restrict__ bbA,
    bf16* __restrict__ bbB, int doGru) {
  __shared__ __align__(16) bf16 smem[32768];   // 64 KB
  const int bx = blockIdx.x;
  const int xcd = bx & 7, j = bx >> 3;
  const int tid = threadIdx.x, wv = tid >> 6, lane = tid & 63;
  const int l16 = lane & 15, k8 = lane >> 4;
  const int wr = (wv >> 1) * 32, wc = (wv & 1) * 32;

  if (j < 16) {
    // ======== hidden role: hidden = relu(state @ WtpT^T + actb_t), 64x64 tile
    if (!doHidden) return;
    const int n0 = xcd * 256 + (j & 3) * 64, m0 = (j >> 2) * 64;
    f32x4 acc[2][2] = {};
    stage_tile_sw<64>(stateb + (size_t)m0 * kS, kS, smem);
    stage_tile_sw<64>(WtpT + (size_t)n0 * kS, kS, smem + 8192);
    __syncthreads();
    for (int kt = 0; kt < kS / 64; ++kt) {
      const int cur = kt & 1;
      bf16* As = smem + cur * 4096;
      bf16* Bs = smem + 8192 + cur * 4096;
      if (kt + 1 < kS / 64) {
        stage_tile_sw<64>(stateb + (size_t)m0 * kS + (kt + 1) * 64, kS,
                          smem + (cur ^ 1) * 4096);
        stage_tile_sw<64>(WtpT + (size_t)n0 * kS + (kt + 1) * 64, kS,
                          smem + 8192 + (cur ^ 1) * 4096);
      }
#pragma unroll
      for (int ks = 0; ks < 2; ++ks) {
        bf16x8 a0 = ldfrag_sw(As, wr, ks), a1 = ldfrag_sw(As, wr + 16, ks);
        bf16x8 b0 = ldfrag_sw(Bs, wc, ks), b1 = ldfrag_sw(Bs, wc + 16, ks);
        acc[0][0] = mfma16(a0, b0, acc[0][0]);
        acc[0][1] = mfma16(a0, b1, acc[0][1]);
        acc[1][0] = mfma16(a1, b0, acc[1][0]);
        acc[1][1] = mfma16(a1, b1, acc[1][1]);
      }
      __syncthreads();
    }
#pragma unroll
    for (int mi = 0; mi < 2; ++mi)
#pragma unroll
      for (int ni = 0; ni < 2; ++ni)
#pragma unroll
        for (int ii = 0; ii < 4; ++ii) {
          int row = m0 + wr + mi * 16 + k8 * 4 + ii;
          int col = n0 + wc + ni * 16 + l16;
          float h = acc[mi][ni][ii] + __bfloat162float(actb_t[(size_t)row * kH + col]);
          hidden_t[(size_t)row * kH + col] = __float2bfloat16(fmaxf(h, 0.f));
        }
  } else {
    // ======== gru role: gh GEMM (3 gates) + fused GRU elementwise, step t-1
    if (!doGru) return;
    const int jj = j - 16;
    const int n0 = xcd * 256 + (jj & 3) * 64, m0 = (jj >> 2) * 64;
    f32x4 acc[3][2][2] = {};
    stage_tile_sw<64>(bbA + (size_t)m0 * kH, kH, smem);
#pragma unroll
    for (int g = 0; g < 3; ++g)
      stage_tile_sw<64>(Whh + (size_t)(g * kH + n0) * kH, kH, smem + 8192 + g * 4096);
    __syncthreads();
    for (int kt = 0; kt < kH / 64; ++kt) {
      const int cur = kt & 1;
      bf16* As = smem + cur * 4096;
      bf16* Bsb = smem + 8192 + cur * 12288;
      if (kt + 1 < kH / 64) {
        stage_tile_sw<64>(bbA + (size_t)m0 * kH + (kt + 1) * 64, kH,
                          smem + (cur ^ 1) * 4096);
#pragma unroll
        for (int g = 0; g < 3; ++g)
          stage_tile_sw<64>(Whh + (size_t)(g * kH + n0) * kH + (kt + 1) * 64, kH,
                            smem + 8192 + (cur ^ 1) * 12288 + g * 4096);
      }
#pragma unroll
      for (int ks = 0; ks < 2; ++ks) {
        bf16x8 a0 = ldfrag_sw(As, wr, ks), a1 = ldfrag_sw(As, wr + 16, ks);
#pragma unroll
        for (int g = 0; g < 3; ++g) {
          bf16x8 b0 = ldfrag_sw(Bsb + g * 4096, wc, ks);
          bf16x8 b1 = ldfrag_sw(Bsb + g * 4096, wc + 16, ks);
          acc[g][0][0] = mfma16(a0, b0, acc[g][0][0]);
          acc[g][0][1] = mfma16(a0, b1, acc[g][0][1]);
          acc[g][1][0] = mfma16(a1, b0, acc[g][1][0]);
          acc[g][1][1] = mfma16(a1, b1, acc[g][1][1]);
        }
      }
      __syncthreads();
    }
#pragma unroll
    for (int mi = 0; mi < 2; ++mi)
#pragma unroll
      for (int ni = 0; ni < 2; ++ni)
#pragma unroll
        for (int ii = 0; ii < 4; ++ii) {
          int row = m0 + wr + mi * 16 + k8 * 4 + ii;
          int col = n0 + wc + ni * 16 + l16;
          const bf16* gi = GIprev + (size_t)row * kH3;
          float hr = acc[0][mi][ni][ii] + b_hh[col];
          float hz = acc[1][mi][ni][ii] + b_hh[kH + col];
          float hn = acc[2][mi][ni][ii] + b_hh[2 * kH + col];
          float r = 1.f / (1.f + expf(-(__bfloat162float(gi[col]) + hr)));
          float z = 1.f / (1.f + expf(-(__bfloat162float(gi[kH + col]) + hz)));
          float n = tanhf(__bfloat162float(gi[2 * kH + col]) + r * hn);
          float bel = belief_f32[(size_t)row * kH + col];
          float nb = (1.f - z) * n + z * bel;
          outB_prev[(size_t)row * kH + col] = nb;
          belief_f32[(size_t)row * kH + col] = nb;
          bbB[(size_t)row * kH + col] = __float2bfloat16(nb);
        }
  }
}

// ---------- fused step kernel 2: post(t) [j<16] || gi(t) [j>=16] ----------
// 224 blocks. xcd = bx&7; j = bx>>3 in [0,28).

__global__ __launch_bounds__(256) void k_step2(
    const bf16* __restrict__ hidden_t, const bf16* __restrict__ WpostT,
    const float* __restrict__ b_post, const float* __restrict__ eps_t,
    float* __restrict__ means_t, float* __restrict__ stds_t,
    float* __restrict__ states_t, bf16* __restrict__ stateb,
    const bf16* __restrict__ Wih, const float* __restrict__ b_ih,
    bf16* __restrict__ GIcur) {
  __shared__ __align__(16) bf16 smem[32768];   // 64 KB
  const int bx = blockIdx.x;
  const int xcd = bx & 7, j = bx >> 3;
  const int tid = threadIdx.x, wv = tid >> 6, lane = tid & 63;
  const int l16 = lane & 15, k8 = lane >> 4;

  if (j < 16) {
    // ======== post role: mean/std/state, 64 rows x 32 pairs
    const int p0 = xcd * 128 + (j & 3) * 32, m0 = (j >> 2) * 64;
    const int wr = (wv >> 1) * 32, wpc = (wv & 1) * 16;
    f32x4 accM[2] = {}, accS[2] = {};
    stage_tile_sw<64>(hidden_t + (size_t)m0 * kH, kH, smem);
    stage_tile_sw<32>(WpostT + (size_t)p0 * kH, kH, smem + 8192);
    stage_tile_sw<32>(WpostT + (size_t)(kS + p0) * kH, kH, smem + 12288);
    __syncthreads();
    for (int kt = 0; kt < kH / 64; ++kt) {
      const int cur = kt & 1;
      bf16* As = smem + cur * 4096;
      bf16* BsM = smem + 8192 + cur * 2048;
      bf16* BsS = smem + 12288 + cur * 2048;
      if (kt + 1 < kH / 64) {
        stage_tile_sw<64>(hidden_t + (size_t)m0 * kH + (kt + 1) * 64, kH,
                          smem + (cur ^ 1) * 4096);
        stage_tile_sw<32>(WpostT + (size_t)p0 * kH + (kt + 1) * 64, kH,
                          smem + 8192 + (cur ^ 1) * 2048);
        stage_tile_sw<32>(WpostT + (size_t)(kS + p0) * kH + (kt + 1) * 64, kH,
                          smem + 12288 + (cur ^ 1) * 2048);
      }
#pragma unroll
      for (int ks = 0; ks < 2; ++ks) {
        bf16x8 a0 = ldfrag_sw(As, wr, ks), a1 = ldfrag_sw(As, wr + 16, ks);
        bf16x8 bm = ldfrag_sw(BsM, wpc, ks);
        bf16x8 bs = ldfrag_sw(BsS, wpc, ks);
        accM[0] = mfma16(a0, bm, accM[0]);
        accM[1] = mfma16(a1, bm, accM[1]);
        accS[0] = mfma16(a0, bs, accS[0]);
        accS[1] = mfma16(a1, bs, accS[1]);
      }
      __syncthreads();
    }
#pragma unroll
    for (int mi = 0; mi < 2; ++mi)
#pragma unroll
      for (int ii = 0; ii < 4; ++ii) {
        int row = m0 + wr + mi * 16 + k8 * 4 + ii;
        int p = p0 + wpc + l16;
        float mean = accM[mi][ii] + b_post[p];
        float sraw = accS[mi][ii] + b_post[kS + p];
        float sp = (sraw > 20.f) ? sraw : log1pf(expf(sraw));
        float sv = mean + sp * eps_t[(size_t)row * kS + p];
        means_t[(size_t)row * kS + p] = mean;
        stds_t[(size_t)row * kS + p] = sp;
        states_t[(size_t)row * kS + p] = sv;
        stateb[(size_t)row * kS + p] = __float2bfloat16(sv);
      }
  } else {
    // ======== gi role: GI(t) = hidden(t) @ W_ih^T + b_ih, 128x128 tile, dbuf
    const int jj = j - 16;                       // 0..11
    const int n0 = xcd * 768 + (jj % 6) * 128;   // XCD-affine over 48 n-blocks
    const int m0 = (jj / 6) * 128;
    const int wr = (wv >> 1) * 64, wcg = (wv & 1) * 64;
    f32x4 acc[4][4] = {};
    stage_tile_sw<128>(hidden_t + (size_t)m0 * kH, kH, smem);
    stage_tile_sw<128>(Wih + (size_t)n0 * kH, kH, smem + 16384);
    __syncthreads();
    for (int kt = 0; kt < kH / 64; ++kt) {
      const int cur = kt & 1;
      bf16* As = smem + cur * 8192;
      bf16* Bs = smem + 16384 + cur * 8192;
      if (kt + 1 < kH / 64) {
        stage_tile_sw<128>(hidden_t + (size_t)m0 * kH + (kt + 1) * 64, kH,
                           smem + (cur ^ 1) * 8192);
        stage_tile_sw<128>(Wih + (size_t)n0 * kH + (kt + 1) * 64, kH,
                           smem + 16384 + (cur ^ 1) * 8192);
      }
#pragma unroll
      for (int ks = 0; ks < 2; ++ks) {
        bf16x8 a[4], b[4];
#pragma unroll
        for (int i = 0; i < 4; ++i) a[i] = ldfrag_sw(As, wr + i * 16, ks);
#pragma unroll
        for (int i = 0; i < 4; ++i) b[i] = ldfrag_sw(Bs, wcg + i * 16, ks);
#pragma unroll
        for (int mi = 0; mi < 4; ++mi)
#pragma unroll
          for (int ni = 0; ni < 4; ++ni)
            acc[mi][ni] = mfma16(a[mi], b[ni], acc[mi][ni]);
      }
      __syncthreads();
    }
#pragma unroll
    for (int mi = 0; mi < 4; ++mi)
#pragma unroll
      for (int ni = 0; ni < 4; ++ni)
#pragma unroll
        for (int ii = 0; ii < 4; ++ii) {
          int row = m0 + wr + mi * 16 + k8 * 4 + ii;
          int col = n0 + wcg + ni * 16 + l16;
          GIcur[(size_t)row * kH3 + col] = __float2bfloat16(acc[mi][ni][ii] + b_ih[col]);
        }
  }
}

// ---------- host ----------

extern "C" void kernel_launch(void* const* d_in, const int* in_sizes, int n_in,
                              void* d_out, int out_size, void* d_ws, size_t ws_size,
                              hipStream_t stream) {
  const float* prev_state  = (const float*)d_in[0];
  const float* actions     = (const float*)d_in[1];
  const float* prev_belief = (const float*)d_in[2];
  const float* eps         = (const float*)d_in[3];
  const float* W_ih        = (const float*)d_in[4];
  const float* W_hh        = (const float*)d_in[5];
  const float* b_ih        = (const float*)d_in[6];
  const float* b_hh        = (const float*)d_in[7];
  const float* W_tp        = (const float*)d_in[8];
  const float* b_tp        = (const float*)d_in[9];
  const float* W_post      = (const float*)d_in[10];
  const float* b_post      = (const float*)d_in[11];

  float* out_beliefs = (float*)d_out;                          // [T,B,H]
  float* out_states  = out_beliefs + (size_t)kT * kB * kH;     // [T,B,S]
  float* out_means   = out_states + (size_t)kT * kB * kS;
  float* out_stds    = out_means + (size_t)kT * kB * kS;

  size_t off = 0;
  auto alloc = [&](size_t bytes) {
    void* r = (char*)d_ws + off;
    off += (bytes + 255) & ~(size_t)255;
    return r;
  };
  bf16* Wih_b  = (bf16*)alloc((size_t)kH3 * kH * 2);
  bf16* Whh_b  = (bf16*)alloc((size_t)kH3 * kH * 2);
  bf16* WtpT   = (bf16*)alloc((size_t)kH * kS * 2);     // [H][S]
  bf16* WpostT = (bf16*)alloc((size_t)kS2 * kH * 2);    // [2S][H]
  bf16* actb   = (bf16*)alloc((size_t)kT * kB * kH * 2);
  bf16* hidden = (bf16*)alloc((size_t)kB * kH * 2);     // 1-step buffer
  bf16* stateb = (bf16*)alloc((size_t)kB * kS * 2);
  bf16* bb0    = (bf16*)alloc((size_t)kB * kH * 2);
  bf16* bb1    = (bf16*)alloc((size_t)kB * kH * 2);
  bf16* bb[2]  = {bb0, bb1};
  float* belief_f32 = (float*)alloc((size_t)kB * kH * 4);
  bf16* GI = (bf16*)alloc((size_t)2 * kB * kH3 * 2);    // 2-step ring

  // prep
  k_cvt<<<dim3(kH3 * kH / 1024), 256, 0, stream>>>(W_ih, Wih_b, kH3 * kH);
  k_cvt<<<dim3(kH3 * kH / 1024), 256, 0, stream>>>(W_hh, Whh_b, kH3 * kH);
  k_cvt<<<dim3(kB * kS / 1024), 256, 0, stream>>>(prev_state, stateb, kB * kS);
  k_cvt_belief<<<dim3(kB * kH / 1024), 256, 0, stream>>>(prev_belief, bb0, belief_f32, kB * kH);
  k_transpose<<<dim3(kH / 32, kS / 32), 256, 0, stream>>>(W_tp, WtpT, kS, kH);
  k_transpose<<<dim3(kS2 / 32, kH / 32), 256, 0, stream>>>(W_post, WpostT, kH, kS2);
  k_actb<<<dim3(kT * kB / 64), 256, 0, stream>>>(actions, W_tp + (size_t)kS * kH, b_tp, actb);

  // interleaved chains: 2 launches per step
  for (int t = 0; t < kT; ++t) {
    const int pv = (t + 1) & 1;   // (t-1)&1
    k_step1<<<dim3(256), dim3(256), 0, stream>>>(
        stateb, WtpT, actb + (size_t)t * kB * kH, hidden, 1,
        Whh_b, b_hh, GI + (size_t)pv * kB * kH3, belief_f32,
        out_beliefs + (size_t)(t > 0 ? t - 1 : 0) * kB * kH,
        bb[pv], bb[t & 1], t > 0);
    k_step2<<<dim3(224), dim3(256), 0, stream>>>(
        hidden, WpostT, b_post, eps + (size_t)t * kB * kS,
        out_means + (size_t)t * kB * kS, out_stds + (size_t)t * kB * kS,
        out_states + (size_t)t * kB * kS, stateb,
        Wih_b, b_ih, GI + (size_t)(t & 1) * kB * kH3);
  }
  // tail: gru for t = kT-1
  k_step1<<<dim3(256), dim3(256), 0, stream>>>(
      stateb, WtpT, actb, hidden, 0,
      Whh_b, b_hh, GI + (size_t)((kT - 1) & 1) * kB * kH3, belief_f32,
      out_beliefs + (size_t)(kT - 1) * kB * kH,
      bb[(kT - 1) & 1], bb[kT & 1], 1);
}

// Round 7
// 3633.280 us; speedup vs baseline: 2.9650x; 1.0070x over previous
//
#include <hip/hip_runtime.h>
#include <hip/hip_bf16.h>
#include <math.h>

constexpr int kT = 64, kB = 256, kS = 1024, kA = 32, kH = 2048;
constexpr int kH3 = 3 * kH;   // 6144
constexpr int kS2 = 2 * kS;   // 2048

typedef __hip_bfloat16 bf16;
typedef __bf16 bf16x8 __attribute__((ext_vector_type(8)));
typedef float f32x4 __attribute__((ext_vector_type(4)));

__device__ inline f32x4 mfma16(bf16x8 a, bf16x8 b, f32x4 c) {
  return __builtin_amdgcn_mfma_f32_16x16x32_bf16(a, b, c, 0, 0, 0);
}

__device__ inline void gload16(const void* g, void* l) {
  __builtin_amdgcn_global_load_lds(
      (const __attribute__((address_space(1))) void*)g,
      (__attribute__((address_space(3))) void*)l, 16, 0, 0);
}

// counted-vmcnt pipeline sync: wait own oldest loads, join block, then allow
// new stage issues. "memory" clobber + sched_barrier pin LDS reads/stages.
#define PSYNC(vm)                                              \
  do {                                                         \
    asm volatile("s_waitcnt vmcnt(" #vm ")" ::: "memory");     \
    __builtin_amdgcn_sched_barrier(0);                         \
    __builtin_amdgcn_s_barrier();                              \
    __builtin_amdgcn_sched_barrier(0);                         \
  } while (0)

// ---- BK=32 tile machinery. Tile = [ROWS][32] bf16 (row = 64 B = 4 x 16B
// chunks). Swizzle: chunk ^= (row>>1)&3 (worst-case 2-way bank alias = free).
// LDS dest linear (global_load_lds), source pre-swizzled; read applies the
// same involution (both-sides rule).

template<int ROWS>
__device__ __forceinline__ void stage32(const bf16* __restrict__ g, int ldK, bf16* lds) {
  const int tid = threadIdx.x;
  if constexpr (ROWS == 32) {
    if (tid < 128) {
      const int r = tid >> 2;
      const int cc = (tid & 3) ^ ((r >> 1) & 3);
      gload16(g + (size_t)r * ldK + cc * 8, lds + (tid >> 6) * 512);
    }
  } else {
#pragma unroll
    for (int i = 0; i < ROWS / 64; ++i) {
      const int idx = i * 256 + tid;
      const int r = idx >> 2;
      const int cc = (idx & 3) ^ ((r >> 1) & 3);
      gload16(g + (size_t)r * ldK + cc * 8, lds + (size_t)(i * 4 + (tid >> 6)) * 512);
    }
  }
}

// fragment: lane l -> row row0+(l&15), k = (l>>4)*8..+7 (one 16x16x32 operand)
__device__ __forceinline__ bf16x8 ldfrag32(const bf16* lds, int row0) {
  const int lane = threadIdx.x & 63;
  const int row = row0 + (lane & 15);
  const int c = (lane >> 4) ^ ((row >> 1) & 3);
  return *reinterpret_cast<const bf16x8*>(lds + row * 32 + c * 8);
}

// ---------- prep kernels ----------

__global__ void k_cvt(const float* __restrict__ src, bf16* __restrict__ dst, int n) {
  int i = (blockIdx.x * 256 + threadIdx.x) * 4;
  if (i >= n) return;
  float4 v = *reinterpret_cast<const float4*>(src + i);
  dst[i + 0] = __float2bfloat16(v.x);
  dst[i + 1] = __float2bfloat16(v.y);
  dst[i + 2] = __float2bfloat16(v.z);
  dst[i + 3] = __float2bfloat16(v.w);
}

__global__ void k_cvt_belief(const float* __restrict__ src, bf16* __restrict__ dstb,
                             float* __restrict__ dstf, int n) {
  int i = (blockIdx.x * 256 + threadIdx.x) * 4;
  if (i >= n) return;
  float4 v = *reinterpret_cast<const float4*>(src + i);
  dstb[i + 0] = __float2bfloat16(v.x);
  dstb[i + 1] = __float2bfloat16(v.y);
  dstb[i + 2] = __float2bfloat16(v.z);
  dstb[i + 3] = __float2bfloat16(v.w);
  *reinterpret_cast<float4*>(dstf + i) = v;
}

// src [R][C] f32 -> dst [C][R] bf16
__global__ __launch_bounds__(256) void k_transpose(const float* __restrict__ src,
                                                   bf16* __restrict__ dst, int R, int C) {
  __shared__ float tile[32][33];
  const int c0 = blockIdx.x * 32, r0 = blockIdx.y * 32;
  const int tx = threadIdx.x & 31, ty = threadIdx.x >> 5;
#pragma unroll
  for (int i = 0; i < 32; i += 8)
    tile[ty + i][tx] = src[(size_t)(r0 + ty + i) * C + c0 + tx];
  __syncthreads();
#pragma unroll
  for (int i = 0; i < 32; i += 8)
    dst[(size_t)(c0 + ty + i) * R + r0 + tx] = __float2bfloat16(tile[tx][ty + i]);
}

// actb[tb][h] = b_tp[h] + sum_a actions[tb][a] * Wtpa[a][h]   (K=32)
__global__ __launch_bounds__(256) void k_actb(const float* __restrict__ actions,
                                              const float* __restrict__ Wtpa,
                                              const float* __restrict__ b_tp,
                                              bf16* __restrict__ actb) {
  __shared__ float a_s[64][32];
  const int tb0 = blockIdx.x * 64;
  const int tid = threadIdx.x;
  for (int i = tid; i < 64 * 32 / 4; i += 256) {
    float4 v = *reinterpret_cast<const float4*>(actions + (size_t)tb0 * 32 + i * 4);
    reinterpret_cast<float4*>(&a_s[0][0])[i] = v;
  }
  __syncthreads();
#pragma unroll
  for (int j = 0; j < 8; ++j) {
    const int c = j * 256 + tid;
    float w[32];
#pragma unroll
    for (int a = 0; a < 32; ++a) w[a] = Wtpa[a * kH + c];
    const float bt = b_tp[c];
    for (int r = 0; r < 64; ++r) {
      float acc = bt;
#pragma unroll
      for (int a = 0; a < 32; ++a) acc += a_s[r][a] * w[a];
      actb[(size_t)(tb0 + r) * kH + c] = __float2bfloat16(acc);
    }
  }
}

// ---------- fused step kernel 1: hidden(t) [j<16] || gru(t-1) [j>=16] ----------
// 256 blocks, 1/CU. DEPTH-4 ring, counted vmcnt, raw s_barrier.

__global__ __launch_bounds__(256) void k_step1(
    const bf16* __restrict__ stateb, const bf16* __restrict__ WtpT,
    const bf16* __restrict__ actb_t, bf16* __restrict__ hidden_t, int doHidden,
    const bf16* __restrict__ Whh, const float* __restrict__ b_hh,
    const bf16* __restrict__ GIprev, float* __restrict__ belief_f32,
    float* __restrict__ outB_prev, const bf16* __restrict__ bbA,
    bf16* __restrict__ bbB, int doGru) {
  __shared__ __align__(16) bf16 smem[32768];   // 64 KB
  const int bx = blockIdx.x;
  const int xcd = bx & 7, j = bx >> 3;
  const int tid = threadIdx.x, wv = tid >> 6, lane = tid & 63;
  const int l16 = lane & 15, k8 = lane >> 4;
  const int wr = (wv >> 1) * 32, wc = (wv & 1) * 32;

  if (j < 16) {
    // ======== hidden = relu(state @ WtpT^T + actb_t); 64x64 tile, NT=32, L=2
    if (!doHidden) return;
    const int n0 = xcd * 256 + (j & 3) * 64, m0 = (j >> 2) * 64;
    const bf16* Ag = stateb + (size_t)m0 * kS;
    const bf16* Bg = WtpT + (size_t)n0 * kS;
    f32x4 acc[2][2] = {};
#define STG_H(t, s)                                            \
  {                                                            \
    stage32<64>(Ag + (t) * 32, kS, smem + (s) * 4096);         \
    stage32<64>(Bg + (t) * 32, kS, smem + (s) * 4096 + 2048);  \
  }
    STG_H(0, 0); STG_H(1, 1); STG_H(2, 2);
    for (int kt = 0; kt < 32; ++kt) {
      if (kt < 30) PSYNC(4);
      else if (kt == 30) PSYNC(2);
      else PSYNC(0);
      if (kt + 3 < 32) STG_H(kt + 3, (kt + 3) & 3);
      const bf16* As = smem + (kt & 3) * 4096;
      const bf16* Bs = As + 2048;
      bf16x8 a0 = ldfrag32(As, wr), a1 = ldfrag32(As, wr + 16);
      bf16x8 b0 = ldfrag32(Bs, wc), b1 = ldfrag32(Bs, wc + 16);
      acc[0][0] = mfma16(a0, b0, acc[0][0]);
      acc[0][1] = mfma16(a0, b1, acc[0][1]);
      acc[1][0] = mfma16(a1, b0, acc[1][0]);
      acc[1][1] = mfma16(a1, b1, acc[1][1]);
    }
#pragma unroll
    for (int mi = 0; mi < 2; ++mi)
#pragma unroll
      for (int ni = 0; ni < 2; ++ni)
#pragma unroll
        for (int ii = 0; ii < 4; ++ii) {
          int row = m0 + wr + mi * 16 + k8 * 4 + ii;
          int col = n0 + wc + ni * 16 + l16;
          float h = acc[mi][ni][ii] + __bfloat162float(actb_t[(size_t)row * kH + col]);
          hidden_t[(size_t)row * kH + col] = __float2bfloat16(fmaxf(h, 0.f));
        }
  } else {
    // ======== gru(t-1): 3-gate gh GEMM + fused elementwise; NT=64, L=4
    if (!doGru) return;
    const int jj = j - 16;
    const int n0 = xcd * 256 + (jj & 3) * 64, m0 = (jj >> 2) * 64;
    const bf16* Ag = bbA + (size_t)m0 * kH;
    const bf16* G0 = Whh + (size_t)(0 * kH + n0) * kH;
    const bf16* G1 = Whh + (size_t)(1 * kH + n0) * kH;
    const bf16* G2 = Whh + (size_t)(2 * kH + n0) * kH;
    f32x4 acc[3][2][2] = {};
#define STG_G(t, s)                                            \
  {                                                            \
    stage32<64>(Ag + (t) * 32, kH, smem + (s) * 8192);         \
    stage32<64>(G0 + (t) * 32, kH, smem + (s) * 8192 + 2048);  \
    stage32<64>(G1 + (t) * 32, kH, smem + (s) * 8192 + 4096);  \
    stage32<64>(G2 + (t) * 32, kH, smem + (s) * 8192 + 6144);  \
  }
    STG_G(0, 0); STG_G(1, 1); STG_G(2, 2);
    for (int kt = 0; kt < 64; ++kt) {
      if (kt < 62) PSYNC(8);
      else if (kt == 62) PSYNC(4);
      else PSYNC(0);
      if (kt + 3 < 64) STG_G(kt + 3, (kt + 3) & 3);
      const bf16* As = smem + (kt & 3) * 8192;
      bf16x8 a0 = ldfrag32(As, wr), a1 = ldfrag32(As, wr + 16);
#pragma unroll
      for (int g = 0; g < 3; ++g) {
        const bf16* Bs = As + 2048 * (1 + g);
        bf16x8 b0 = ldfrag32(Bs, wc), b1 = ldfrag32(Bs, wc + 16);
        acc[g][0][0] = mfma16(a0, b0, acc[g][0][0]);
        acc[g][0][1] = mfma16(a0, b1, acc[g][0][1]);
        acc[g][1][0] = mfma16(a1, b0, acc[g][1][0]);
        acc[g][1][1] = mfma16(a1, b1, acc[g][1][1]);
      }
    }
#pragma unroll
    for (int mi = 0; mi < 2; ++mi)
#pragma unroll
      for (int ni = 0; ni < 2; ++ni)
#pragma unroll
        for (int ii = 0; ii < 4; ++ii) {
          int row = m0 + wr + mi * 16 + k8 * 4 + ii;
          int col = n0 + wc + ni * 16 + l16;
          const bf16* gi = GIprev + (size_t)row * kH3;
          float hr = acc[0][mi][ni][ii] + b_hh[col];
          float hz = acc[1][mi][ni][ii] + b_hh[kH + col];
          float hn = acc[2][mi][ni][ii] + b_hh[2 * kH + col];
          float r = 1.f / (1.f + expf(-(__bfloat162float(gi[col]) + hr)));
          float z = 1.f / (1.f + expf(-(__bfloat162float(gi[kH + col]) + hz)));
          float n = tanhf(__bfloat162float(gi[2 * kH + col]) + r * hn);
          float bel = belief_f32[(size_t)row * kH + col];
          float nb = (1.f - z) * n + z * bel;
          outB_prev[(size_t)row * kH + col] = nb;
          belief_f32[(size_t)row * kH + col] = nb;
          bbB[(size_t)row * kH + col] = __float2bfloat16(nb);
        }
  }
}

// ---------- fused step kernel 2: post(t) [j<16] || gi(t) [j>=16] ----------
// 224 blocks. DEPTH-4 ring pipelines.

__global__ __launch_bounds__(256) void k_step2(
    const bf16* __restrict__ hidden_t, const bf16* __restrict__ WpostT,
    const float* __restrict__ b_post, const float* __restrict__ eps_t,
    float* __restrict__ means_t, float* __restrict__ stds_t,
    float* __restrict__ states_t, bf16* __restrict__ stateb,
    const bf16* __restrict__ Wih, const float* __restrict__ b_ih,
    bf16* __restrict__ GIcur) {
  __shared__ __align__(16) bf16 smem[32768];   // 64 KB
  const int bx = blockIdx.x;
  const int xcd = bx & 7, j = bx >> 3;
  const int tid = threadIdx.x, wv = tid >> 6, lane = tid & 63;
  const int l16 = lane & 15, k8 = lane >> 4;

  if (j < 16) {
    // ======== post: mean/std/state; 64 rows x 32 pairs; NT=64, L=3
    const int p0 = xcd * 128 + (j & 3) * 32, m0 = (j >> 2) * 64;
    const int wr = (wv >> 1) * 32, wpc = (wv & 1) * 16;
    const bf16* Ag = hidden_t + (size_t)m0 * kH;
    const bf16* Mg = WpostT + (size_t)p0 * kH;
    const bf16* Sg = WpostT + (size_t)(kS + p0) * kH;
    f32x4 accM[2] = {}, accS[2] = {};
#define STG_P(t, s)                                            \
  {                                                            \
    stage32<64>(Ag + (t) * 32, kH, smem + (s) * 4096);         \
    stage32<32>(Mg + (t) * 32, kH, smem + (s) * 4096 + 2048);  \
    stage32<32>(Sg + (t) * 32, kH, smem + (s) * 4096 + 3072);  \
  }
    STG_P(0, 0); STG_P(1, 1); STG_P(2, 2);
    for (int kt = 0; kt < 64; ++kt) {
      if (kt < 62) PSYNC(6);
      else if (kt == 62) PSYNC(3);
      else PSYNC(0);
      if (kt + 3 < 64) STG_P(kt + 3, (kt + 3) & 3);
      const bf16* As = smem + (kt & 3) * 4096;
      bf16x8 a0 = ldfrag32(As, wr), a1 = ldfrag32(As, wr + 16);
      bf16x8 bm = ldfrag32(As + 2048, wpc);
      bf16x8 bs = ldfrag32(As + 3072, wpc);
      accM[0] = mfma16(a0, bm, accM[0]);
      accM[1] = mfma16(a1, bm, accM[1]);
      accS[0] = mfma16(a0, bs, accS[0]);
      accS[1] = mfma16(a1, bs, accS[1]);
    }
#pragma unroll
    for (int mi = 0; mi < 2; ++mi)
#pragma unroll
      for (int ii = 0; ii < 4; ++ii) {
        int row = m0 + wr + mi * 16 + k8 * 4 + ii;
        int p = p0 + wpc + l16;
        float mean = accM[mi][ii] + b_post[p];
        float sraw = accS[mi][ii] + b_post[kS + p];
        float sp = (sraw > 20.f) ? sraw : log1pf(expf(sraw));
        float sv = mean + sp * eps_t[(size_t)row * kS + p];
        means_t[(size_t)row * kS + p] = mean;
        stds_t[(size_t)row * kS + p] = sp;
        states_t[(size_t)row * kS + p] = sv;
        stateb[(size_t)row * kS + p] = __float2bfloat16(sv);
      }
  } else {
    // ======== gi: GI(t) = hidden(t) @ W_ih^T + b_ih; 128x128 tile; NT=64, L=4
    const int jj = j - 16;                       // 0..11
    const int n0 = xcd * 768 + (jj % 6) * 128;   // XCD-affine over 48 n-blocks
    const int m0 = (jj / 6) * 128;
    const int wrg = (wv >> 1) * 64, wcg = (wv & 1) * 64;
    const bf16* Ag = hidden_t + (size_t)m0 * kH;
    const bf16* Bg = Wih + (size_t)n0 * kH;
    f32x4 acc[4][4] = {};
#define STG_I(t, s)                                             \
  {                                                             \
    stage32<128>(Ag + (t) * 32, kH, smem + (s) * 8192);         \
    stage32<128>(Bg + (t) * 32, kH, smem + (s) * 8192 + 4096);  \
  }
    STG_I(0, 0); STG_I(1, 1); STG_I(2, 2);
    for (int kt = 0; kt < 64; ++kt) {
      if (kt < 62) PSYNC(8);
      else if (kt == 62) PSYNC(4);
      else PSYNC(0);
      if (kt + 3 < 64) STG_I(kt + 3, (kt + 3) & 3);
      const bf16* As = smem + (kt & 3) * 8192;
      const bf16* Bs = As + 4096;
      bf16x8 a[4], b[4];
#pragma unroll
      for (int i = 0; i < 4; ++i) a[i] = ldfrag32(As, wrg + i * 16);
#pragma unroll
      for (int i = 0; i < 4; ++i) b[i] = ldfrag32(Bs, wcg + i * 16);
#pragma unroll
      for (int mi = 0; mi < 4; ++mi)
#pragma unroll
        for (int ni = 0; ni < 4; ++ni)
          acc[mi][ni] = mfma16(a[mi], b[ni], acc[mi][ni]);
    }
#pragma unroll
    for (int mi = 0; mi < 4; ++mi)
#pragma unroll
      for (int ni = 0; ni < 4; ++ni)
#pragma unroll
        for (int ii = 0; ii < 4; ++ii) {
          int row = m0 + wrg + mi * 16 + k8 * 4 + ii;
          int col = n0 + wcg + ni * 16 + l16;
          GIcur[(size_t)row * kH3 + col] = __float2bfloat16(acc[mi][ni][ii] + b_ih[col]);
        }
  }
}

// ---------- host ----------

extern "C" void kernel_launch(void* const* d_in, const int* in_sizes, int n_in,
                              void* d_out, int out_size, void* d_ws, size_t ws_size,
                              hipStream_t stream) {
  const float* prev_state  = (const float*)d_in[0];
  const float* actions     = (const float*)d_in[1];
  const float* prev_belief = (const float*)d_in[2];
  const float* eps         = (const float*)d_in[3];
  const float* W_ih        = (const float*)d_in[4];
  const float* W_hh        = (const float*)d_in[5];
  const float* b_ih        = (const float*)d_in[6];
  const float* b_hh        = (const float*)d_in[7];
  const float* W_tp        = (const float*)d_in[8];
  const float* b_tp        = (const float*)d_in[9];
  const float* W_post      = (const float*)d_in[10];
  const float* b_post      = (const float*)d_in[11];

  float* out_beliefs = (float*)d_out;                          // [T,B,H]
  float* out_states  = out_beliefs + (size_t)kT * kB * kH;     // [T,B,S]
  float* out_means   = out_states + (size_t)kT * kB * kS;
  float* out_stds    = out_means + (size_t)kT * kB * kS;

  size_t off = 0;
  auto alloc = [&](size_t bytes) {
    void* r = (char*)d_ws + off;
    off += (bytes + 255) & ~(size_t)255;
    return r;
  };
  bf16* Wih_b  = (bf16*)alloc((size_t)kH3 * kH * 2);
  bf16* Whh_b  = (bf16*)alloc((size_t)kH3 * kH * 2);
  bf16* WtpT   = (bf16*)alloc((size_t)kH * kS * 2);     // [H][S]
  bf16* WpostT = (bf16*)alloc((size_t)kS2 * kH * 2);    // [2S][H]
  bf16* actb   = (bf16*)alloc((size_t)kT * kB * kH * 2);
  bf16* hidden = (bf16*)alloc((size_t)kB * kH * 2);     // 1-step buffer
  bf16* stateb = (bf16*)alloc((size_t)kB * kS * 2);
  bf16* bb0    = (bf16*)alloc((size_t)kB * kH * 2);
  bf16* bb1    = (bf16*)alloc((size_t)kB * kH * 2);
  bf16* bb[2]  = {bb0, bb1};
  float* belief_f32 = (float*)alloc((size_t)kB * kH * 4);
  bf16* GI = (bf16*)alloc((size_t)2 * kB * kH3 * 2);    // 2-step ring

  // prep
  k_cvt<<<dim3(kH3 * kH / 1024), 256, 0, stream>>>(W_ih, Wih_b, kH3 * kH);
  k_cvt<<<dim3(kH3 * kH / 1024), 256, 0, stream>>>(W_hh, Whh_b, kH3 * kH);
  k_cvt<<<dim3(kB * kS / 1024), 256, 0, stream>>>(prev_state, stateb, kB * kS);
  k_cvt_belief<<<dim3(kB * kH / 1024), 256, 0, stream>>>(prev_belief, bb0, belief_f32, kB * kH);
  k_transpose<<<dim3(kH / 32, kS / 32), 256, 0, stream>>>(W_tp, WtpT, kS, kH);
  k_transpose<<<dim3(kS2 / 32, kH / 32), 256, 0, stream>>>(W_post, WpostT, kH, kS2);
  k_actb<<<dim3(kT * kB / 64), 256, 0, stream>>>(actions, W_tp + (size_t)kS * kH, b_tp, actb);

  // interleaved chains: 2 launches per step
  for (int t = 0; t < kT; ++t) {
    const int pv = (t + 1) & 1;   // (t-1)&1
    k_step1<<<dim3(256), dim3(256), 0, stream>>>(
        stateb, WtpT, actb + (size_t)t * kB * kH, hidden, 1,
        Whh_b, b_hh, GI + (size_t)pv * kB * kH3, belief_f32,
        out_beliefs + (size_t)(t > 0 ? t - 1 : 0) * kB * kH,
        bb[pv], bb[t & 1], t > 0);
    k_step2<<<dim3(224), dim3(256), 0, stream>>>(
        hidden, WpostT, b_post, eps + (size_t)t * kB * kS,
        out_means + (size_t)t * kB * kS, out_stds + (size_t)t * kB * kS,
        out_states + (size_t)t * kB * kS, stateb,
        Wih_b, b_ih, GI + (size_t)(t & 1) * kB * kH3);
  }
  // tail: gru for t = kT-1
  k_step1<<<dim3(256), dim3(256), 0, stream>>>(
      stateb, WtpT, actb, hidden, 0,
      Whh_b, b_hh, GI + (size_t)((kT - 1) & 1) * kB * kH3, belief_f32,
      out_beliefs + (size_t)(kT - 1) * kB * kH,
      bb[(kT - 1) & 1], bb[kT & 1], 1);
}